// Round 8
// baseline (247.466 us; speedup 1.0000x reference)
//
#include <hip/hip_runtime.h>
#include <math.h>

// Fused net, round 8: round-7 structure (streamed B-frags, zeroed pads) +
// __launch_bounds__(256, 8). Round 7 proved the allocator won't target the 64-VGPR
// occupancy boundary voluntarily (picked 68 with ~40 live); round 6's cap failure
// was the 20-resident-B-frag phase 3, which round 7 removed. Cap should now close
// spill-free: detectors are WRITE_SIZE (spill) and post-timing absmax (drift).

typedef __attribute__((ext_vector_type(8))) short bf16x8;
typedef __attribute__((ext_vector_type(4))) float f32x4;

union Frag { short4 h[2]; bf16x8 v; };

static __device__ __forceinline__ unsigned short f2bf(float f) {
    union { float f; unsigned u; } v; v.f = f;
    unsigned r = v.u + 0x7FFFu + ((v.u >> 16) & 1u);   // RNE
    return (unsigned short)(r >> 16);
}

#define MFMA(a, b, c) __builtin_amdgcn_mfma_f32_16x16x32_bf16((a), (b), (c), 0, 0, 0)

// ---------------- B-fragment prepack: 31 frags x 64 lanes x 8 bf16 ----------------
// fid 0..5  : linear  B[k][j]=W[j][k], fid=ks*3+nt (K=48 -> 2 steps, N=48 -> 3 tiles)
// fid 6..10 : conv1   ky=fid-6; window elem e=kx*4+icp (pixel stride 4)
// fid 11..30: conv2   fid-11 = nt*10+ky*2+s; window elem idx=32s+kap, idx=kx*12+icp
__global__ __launch_bounds__(64)
void prepack(const float* __restrict__ W, const float* __restrict__ w1,
             const float* __restrict__ w2, unsigned short* __restrict__ ws) {
    const int fid = blockIdx.x;
    const int lane = threadIdx.x;
    const int col = lane & 15, grp = lane >> 4;
    unsigned short tmp[8];
    #pragma unroll
    for (int e = 0; e < 8; ++e) {
        const int kap = 16 * (e >> 2) + 4 * grp + (e & 3);   // 0..31
        float v = 0.f;
        if (fid < 6) {
            const int ks = fid / 3, nt = fid % 3;
            const int k = 32 * ks + kap, j = 16 * nt + col;
            if (k < 48) v = W[j * 48 + k];
        } else if (fid < 11) {
            const int ky = fid - 6;
            const int kx = kap >> 2, icp = kap & 3;
            if (kx < 5 && icp < 3 && col < 10)
                v = w1[col * 75 + icp * 25 + ky * 5 + kx];
        } else {
            const int r = fid - 11, nt = r / 10, ky = (r % 10) >> 1, s = r & 1;
            const int idx = 32 * s + kap;
            const int kx = idx / 12, icp = idx % 12, oc = 16 * nt + col;
            if (kx < 5 && icp < 10 && oc < 20)
                v = w2[oc * 250 + icp * 25 + ky * 5 + kx];
        }
        tmp[e] = f2bf(v);
    }
    Frag f;
    f.h[0] = make_short4((short)tmp[0], (short)tmp[1], (short)tmp[2], (short)tmp[3]);
    f.h[1] = make_short4((short)tmp[4], (short)tmp[5], (short)tmp[6], (short)tmp[7]);
    *(bf16x8*)(ws + fid * 512 + lane * 8) = f.v;
}

// ---------------- main fused kernel: one block (256 thr) per image ----------------
#define RS1 136   // s_img row stride (elems): 32 cols * 4ch + 8 pad
#define RS2 168   // s_h1 row stride (elems): 14 cols * 12ch

__global__ __launch_bounds__(256, 8)
void fused_net(const float* __restrict__ x,    // [B,32,32,3] NHWC f32
               const unsigned short* __restrict__ ws, // prepacked B-frags
               const float* __restrict__ b1,   // [10]
               const float* __restrict__ b2,   // [20]
               const float* __restrict__ fw1,  // [50,500]
               const float* __restrict__ fb1,  // [50]
               const float* __restrict__ fw2,  // [10,50]
               const float* __restrict__ fb2,  // [10]
               float* __restrict__ out)        // [B,10]
{
    const int b    = blockIdx.x;
    const int tid  = threadIdx.x;
    const int wave = __builtin_amdgcn_readfirstlane(tid >> 6);
    const int lane = tid & 63;
    const int col16 = lane & 15, grp = lane >> 4;

    __shared__ unsigned short s_img[32 * RS1 + 64];  // HWC4 bf16 + zeroed pads/tail
    __shared__ unsigned short s_h1[14 * RS2 + 64];   // HWC12 bf16 + zeroed tail
    __shared__ float s_h2[500];
    __shared__ float s_part[256];
    __shared__ float s_f1[56];
    __shared__ float s_lg[16];

    // ---------------- Phase 1: linear via MFMA -> s_img (HWC4 bf16) ----------------
    {
        const int blkA = 16 * wave + col16;
        const float* xb = x + (size_t)b * 3072 + (blkA >> 3) * 384 + (blkA & 7) * 12;
        const int k0 = 4 * grp,      o0 = (k0 / 12) * 96 + (k0 % 12);
        const int k1 = 16 + 4 * grp, o1 = (k1 / 12) * 96 + (k1 % 12);
        const int k2 = 32 + 4 * grp, o2 = (k2 / 12) * 96 + (k2 % 12);
        const float4 fa = *(const float4*)(xb + o0);
        const float4 fb = *(const float4*)(xb + o1);
        const float4 fc = *(const float4*)(xb + o2);
        Frag a0, a1;
        a0.h[0] = make_short4((short)f2bf(fa.x), (short)f2bf(fa.y), (short)f2bf(fa.z), (short)f2bf(fa.w));
        a0.h[1] = make_short4((short)f2bf(fb.x), (short)f2bf(fb.y), (short)f2bf(fb.z), (short)f2bf(fb.w));
        a1.h[0] = make_short4((short)f2bf(fc.x), (short)f2bf(fc.y), (short)f2bf(fc.z), (short)f2bf(fc.w));
        a1.h[1] = make_short4(0, 0, 0, 0);        // k>=48 pad: zero (also avoids OOB x reads)

        #pragma unroll
        for (int nt = 0; nt < 3; ++nt) {
            Frag bl0, bl1;                        // streamed from L2, not resident
            bl0.v = *(const bf16x8*)(ws + nt * 512 + lane * 8);
            bl1.v = *(const bf16x8*)(ws + (3 + nt) * 512 + lane * 8);
            f32x4 acc = {0.f, 0.f, 0.f, 0.f};
            acc = MFMA(a0.v, bl0.v, acc);
            acc = MFMA(a1.v, bl1.v, acc);
            const int j = 16 * nt + col16;                 // output k' index
            const int di = j / 12, dj = (j % 12) / 3, cch = j % 3;
            #pragma unroll
            for (int r = 0; r < 4; ++r) {
                const int blk = 16 * wave + 4 * grp + r;   // C row = block id
                const int row = (blk >> 3) * 4 + di, cp = (blk & 7) * 4 + dj;
                s_img[row * RS1 + cp * 4 + cch] = f2bf(acc[r]);
            }
        }
    }
    // zero pad-channel 3, row pads (cols 128..135), and LDS tails: no uninit reads ever
    for (int p = tid; p < 1024; p += 256)
        s_img[(p >> 5) * RS1 + (p & 31) * 4 + 3] = 0;
    if (tid < 256) s_img[(tid >> 3) * RS1 + 128 + (tid & 7)] = 0;
    if (tid < 64) s_img[32 * RS1 + tid] = 0;
    if (tid < 64) s_h1[14 * RS2 + tid] = 0;
    __syncthreads();

    // ---------------- Phase 2: conv1+pool+relu via MFMA -> s_h1 (HWC12 bf16) ----------------
    // M = 784 conv pixels in quad order; 49 M-tiles, 5 K-steps (ky), N=10 (1 tile).
    {
        Frag bc1[5];                              // resident: phase-2 peak ~45 VGPR
        #pragma unroll
        for (int f = 0; f < 5; ++f)
            bc1[f].v = *(const bf16x8*)(ws + (6 + f) * 512 + lane * 8);
        const float bias1 = b1[col16 < 10 ? col16 : 0];

        for (int t = wave; t < 49; t += 4) {
            const int q = 4 * t + (col16 >> 2), sub = col16 & 3;   // A row m = col16
            const int oi = q / 14, oj = q % 14;
            const int ci = 2 * oi + (sub >> 1), cj = 2 * oj + (sub & 1);
            const int base = ci * RS1 + cj * 4 + 4 * grp;
            f32x4 acc = {0.f, 0.f, 0.f, 0.f};
            #pragma unroll
            for (int ky = 0; ky < 5; ++ky) {
                Frag a;
                a.h[0] = *(const short4*)&s_img[base + ky * RS1];
                a.h[1] = *(const short4*)&s_img[base + ky * RS1 + 16];
                acc = MFMA(a.v, bc1[ky].v, acc);
            }
            const int qo = 4 * t + grp;          // C rows 4*grp..+3 = one pool quad
            if (col16 < 12) {
                const float pm = fmaxf(fmaxf(acc[0], acc[1]), fmaxf(acc[2], acc[3]));
                const float val = fmaxf(pm + bias1, 0.f);
                s_h1[(qo / 14) * RS2 + (qo % 14) * 12 + col16] =
                    (col16 < 10) ? f2bf(val) : (unsigned short)0;
            }
        }
    }
    __syncthreads();

    // ---------------- Phase 3: conv2+pool+relu via MFMA -> s_h2 (f32, flatten order) ----------------
    // M = 100 conv pixels in quad order (25 quads -> 7 M-tiles); 10 K-steps; N = 2 tiles.
    // B-frags streamed per K-step (L2-hot, 16B/lane) -> only 2 frags live at a time.
    {
        const int oc1 = 16 + col16;
        const float bias20 = b2[col16];                    // col16 <= 15 < 20
        const float bias21 = b2[oc1 < 20 ? oc1 : 0];

        for (int t = wave; t < 7; t += 4) {
            int q = 4 * t + (col16 >> 2); if (q > 24) q = 24;   // clamp garbage rows in-bounds
            const int sub = col16 & 3;
            const int oi = q / 5, oj = q % 5;
            const int ci = 2 * oi + (sub >> 1), cj = 2 * oj + (sub & 1);
            const int base = ci * RS2 + cj * 12 + 4 * grp;
            f32x4 acc0 = {0.f, 0.f, 0.f, 0.f}, acc1 = {0.f, 0.f, 0.f, 0.f};
            #pragma unroll
            for (int ky = 0; ky < 5; ++ky) {
                #pragma unroll
                for (int s = 0; s < 2; ++s) {
                    Frag a, bb0, bb1;
                    a.h[0] = *(const short4*)&s_h1[base + ky * RS2 + 32 * s];
                    a.h[1] = *(const short4*)&s_h1[base + ky * RS2 + 32 * s + 16];
                    bb0.v = *(const bf16x8*)(ws + (11 + ky * 2 + s) * 512 + lane * 8);
                    bb1.v = *(const bf16x8*)(ws + (21 + ky * 2 + s) * 512 + lane * 8);
                    acc0 = MFMA(a.v, bb0.v, acc0);
                    acc1 = MFMA(a.v, bb1.v, acc1);
                }
            }
            const int qo = 4 * t + grp;
            if (qo < 25) {
                const float p0 = fmaxf(fmaxf(acc0[0], acc0[1]), fmaxf(acc0[2], acc0[3]));
                s_h2[col16 * 25 + qo] = fmaxf(p0 + bias20, 0.f);
                if (oc1 < 20) {
                    const float p1 = fmaxf(fmaxf(acc1[0], acc1[1]), fmaxf(acc1[2], acc1[3]));
                    s_h2[oc1 * 25 + qo] = fmaxf(p1 + bias21, 0.f);
                }
            }
        }
    }
    __syncthreads();

    // ---------------- Phase 4: fc1 (500->50) split 5-way + relu ----------------
    if (tid < 250) {
        const int oc = tid / 5, part = tid % 5;
        const float* wr = fw1 + oc * 500 + part * 100;
        const float* hp = s_h2 + part * 100;
        float a = 0.f;
        #pragma unroll
        for (int i = 0; i < 25; ++i) {
            const float4 wv = *reinterpret_cast<const float4*>(wr + i * 4);
            const float4 hv = *reinterpret_cast<const float4*>(hp + i * 4);
            a += wv.x * hv.x + wv.y * hv.y + wv.z * hv.z + wv.w * hv.w;
        }
        s_part[tid] = a;
    }
    __syncthreads();
    if (tid < 50) {
        float a = fb1[tid];
        #pragma unroll
        for (int j = 0; j < 5; ++j) a += s_part[tid * 5 + j];
        s_f1[tid] = fmaxf(a, 0.f);
    }
    __syncthreads();

    // ---------------- Phase 5: fc2 (50->10) ----------------
    if (tid < 10) {
        const float* wr = fw2 + tid * 50;
        float a = fb2[tid];
        for (int k = 0; k < 50; ++k) a += s_f1[k] * wr[k];
        s_lg[tid] = a;
    }
    __syncthreads();

    // ---------------- Phase 6: log_softmax ----------------
    if (tid < 10) {
        float m = s_lg[0];
        for (int k = 1; k < 10; ++k) m = fmaxf(m, s_lg[k]);
        float s = 0.f;
        for (int k = 0; k < 10; ++k) s += expf(s_lg[k] - m);
        out[(size_t)b * 10 + tid] = s_lg[tid] - m - logf(s);
    }
}

extern "C" void kernel_launch(void* const* d_in, const int* in_sizes, int n_in,
                              void* d_out, int out_size, void* d_ws, size_t ws_size,
                              hipStream_t stream) {
    const float* x   = (const float*)d_in[0];
    const float* W   = (const float*)d_in[1];
    const float* w1  = (const float*)d_in[2];
    const float* b1  = (const float*)d_in[3];
    const float* w2  = (const float*)d_in[4];
    const float* b2  = (const float*)d_in[5];
    const float* fw1 = (const float*)d_in[6];
    const float* fb1 = (const float*)d_in[7];
    const float* fw2 = (const float*)d_in[8];
    const float* fb2 = (const float*)d_in[9];
    float* o = (float*)d_out;
    unsigned short* wsp = (unsigned short*)d_ws;

    const int B = in_sizes[0] / 3072;
    prepack<<<dim3(31), dim3(64), 0, stream>>>(W, w1, w2, wsp);
    fused_net<<<dim3(B), dim3(256), 0, stream>>>(x, wsp, b1, b2, fw1, fb1, fw2, fb2, o);
}

// Round 9
// 135.708 us; speedup vs baseline: 1.8235x; 1.8235x over previous
//
#include <hip/hip_runtime.h>
#include <math.h>

// Fused net, round 9: cut L2 stream traffic (the inferred wall: ~2.5 GB/dispatch,
// ~75% of L2 peak inside phase 3).
//  (a) conv2 B-frags staged into LDS once per block (20 KB) at kernel entry
//      (overlaps phase-1 global latency); phase 3 reads them via conflict-free
//      16B-stride ds_read_b128. Per-block B traffic 160 KB -> 20 KB.
//  (b) fc1 weights prepacked to bf16 (halves fc1's 100 KB/block L2 reads).
//  No launch-bounds min-waves clause (rounds 2/6/8: allocator footgun, 3-for-3).

typedef __attribute__((ext_vector_type(8))) short bf16x8;
typedef __attribute__((ext_vector_type(4))) float f32x4;

union Frag { short4 h[2]; bf16x8 v; };

static __device__ __forceinline__ unsigned short f2bf(float f) {
    union { float f; unsigned u; } v; v.f = f;
    unsigned r = v.u + 0x7FFFu + ((v.u >> 16) & 1u);   // RNE
    return (unsigned short)(r >> 16);
}

#define MFMA(a, b, c) __builtin_amdgcn_mfma_f32_16x16x32_bf16((a), (b), (c), 0, 0, 0)

// ---------------- B-fragment prepack: 31 frags x 64 lanes x 8 bf16 ----------------
// fid 0..5  : linear  B[k][j]=W[j][k], fid=ks*3+nt (K=48 -> 2 steps, N=48 -> 3 tiles)
// fid 6..10 : conv1   ky=fid-6; window elem e=kx*4+icp (pixel stride 4)
// fid 11..30: conv2   fid-11 = nt*10+ky*2+s; window elem idx=32s+kap, idx=kx*12+icp
__global__ __launch_bounds__(64)
void prepack(const float* __restrict__ W, const float* __restrict__ w1,
             const float* __restrict__ w2, unsigned short* __restrict__ ws) {
    const int fid = blockIdx.x;
    const int lane = threadIdx.x;
    const int col = lane & 15, grp = lane >> 4;
    unsigned short tmp[8];
    #pragma unroll
    for (int e = 0; e < 8; ++e) {
        const int kap = 16 * (e >> 2) + 4 * grp + (e & 3);   // 0..31
        float v = 0.f;
        if (fid < 6) {
            const int ks = fid / 3, nt = fid % 3;
            const int k = 32 * ks + kap, j = 16 * nt + col;
            if (k < 48) v = W[j * 48 + k];
        } else if (fid < 11) {
            const int ky = fid - 6;
            const int kx = kap >> 2, icp = kap & 3;
            if (kx < 5 && icp < 3 && col < 10)
                v = w1[col * 75 + icp * 25 + ky * 5 + kx];
        } else {
            const int r = fid - 11, nt = r / 10, ky = (r % 10) >> 1, s = r & 1;
            const int idx = 32 * s + kap;
            const int kx = idx / 12, icp = idx % 12, oc = 16 * nt + col;
            if (kx < 5 && icp < 10 && oc < 20)
                v = w2[oc * 250 + icp * 25 + ky * 5 + kx];
        }
        tmp[e] = f2bf(v);
    }
    Frag f;
    f.h[0] = make_short4((short)tmp[0], (short)tmp[1], (short)tmp[2], (short)tmp[3]);
    f.h[1] = make_short4((short)tmp[4], (short)tmp[5], (short)tmp[6], (short)tmp[7]);
    *(bf16x8*)(ws + fid * 512 + lane * 8) = f.v;
}

// ---------------- fc1 weight pack: fw1 [50,500] f32 -> bf16 pairs at ws+16384 ----------------
__global__ __launch_bounds__(256)
void pack_fc1(const float* __restrict__ fw1, unsigned short* __restrict__ ws) {
    const int i = blockIdx.x * 256 + threadIdx.x;   // uint index, 12500 total
    if (i < 12500) {
        const unsigned lo = f2bf(fw1[2 * i]);
        const unsigned hi = f2bf(fw1[2 * i + 1]);
        ((unsigned*)(ws + 16384))[i] = lo | (hi << 16);
    }
}

// ---------------- main fused kernel: one block (256 thr) per image ----------------
#define RS1 136   // s_img row stride (elems): 32 cols * 4ch + 8 pad
#define RS2 168   // s_h1 row stride (elems): 14 cols * 12ch

__global__ __launch_bounds__(256)
void fused_net(const float* __restrict__ x,    // [B,32,32,3] NHWC f32
               const unsigned short* __restrict__ ws, // prepacked B-frags + bf16 fc1 w
               const float* __restrict__ b1,   // [10]
               const float* __restrict__ b2,   // [20]
               const float* __restrict__ fb1,  // [50]
               const float* __restrict__ fw2,  // [10,50]
               const float* __restrict__ fb2,  // [10]
               float* __restrict__ out)        // [B,10]
{
    const int b    = blockIdx.x;
    const int tid  = threadIdx.x;
    const int wave = __builtin_amdgcn_readfirstlane(tid >> 6);
    const int lane = tid & 63;
    const int col16 = lane & 15, grp = lane >> 4;

    __shared__ unsigned short s_img[32 * RS1 + 64];  // HWC4 bf16 + zeroed pads/tail
    __shared__ unsigned short s_h1[14 * RS2 + 64];   // HWC12 bf16 + zeroed tail
    __shared__ unsigned short s_b2[20 * 512];        // conv2 B-frags, staged once
    __shared__ float s_h2[500];
    __shared__ float s_part[256];
    __shared__ float s_f1[56];
    __shared__ float s_lg[16];

    // ---- stage conv2 B-frags (20 KB) LDS-resident; overlaps phase-1 load latency ----
    {
        const uint4* src = (const uint4*)(ws + 11 * 512);   // frags 11..30 contiguous
        uint4* dst = (uint4*)s_b2;
        #pragma unroll
        for (int i = 0; i < 5; ++i)
            dst[tid + 256 * i] = src[tid + 256 * i];
    }

    // ---------------- Phase 1: linear via MFMA -> s_img (HWC4 bf16) ----------------
    {
        const int blkA = 16 * wave + col16;
        const float* xb = x + (size_t)b * 3072 + (blkA >> 3) * 384 + (blkA & 7) * 12;
        const int k0 = 4 * grp,      o0 = (k0 / 12) * 96 + (k0 % 12);
        const int k1 = 16 + 4 * grp, o1 = (k1 / 12) * 96 + (k1 % 12);
        const int k2 = 32 + 4 * grp, o2 = (k2 / 12) * 96 + (k2 % 12);
        const float4 fa = *(const float4*)(xb + o0);
        const float4 fb = *(const float4*)(xb + o1);
        const float4 fc = *(const float4*)(xb + o2);
        Frag a0, a1;
        a0.h[0] = make_short4((short)f2bf(fa.x), (short)f2bf(fa.y), (short)f2bf(fa.z), (short)f2bf(fa.w));
        a0.h[1] = make_short4((short)f2bf(fb.x), (short)f2bf(fb.y), (short)f2bf(fb.z), (short)f2bf(fb.w));
        a1.h[0] = make_short4((short)f2bf(fc.x), (short)f2bf(fc.y), (short)f2bf(fc.z), (short)f2bf(fc.w));
        a1.h[1] = make_short4(0, 0, 0, 0);        // k>=48 pad: zero (also avoids OOB x reads)

        #pragma unroll
        for (int nt = 0; nt < 3; ++nt) {
            Frag bl0, bl1;                        // streamed from L2 (one-shot use)
            bl0.v = *(const bf16x8*)(ws + nt * 512 + lane * 8);
            bl1.v = *(const bf16x8*)(ws + (3 + nt) * 512 + lane * 8);
            f32x4 acc = {0.f, 0.f, 0.f, 0.f};
            acc = MFMA(a0.v, bl0.v, acc);
            acc = MFMA(a1.v, bl1.v, acc);
            const int j = 16 * nt + col16;                 // output k' index
            const int di = j / 12, dj = (j % 12) / 3, cch = j % 3;
            #pragma unroll
            for (int r = 0; r < 4; ++r) {
                const int blk = 16 * wave + 4 * grp + r;   // C row = block id
                const int row = (blk >> 3) * 4 + di, cp = (blk & 7) * 4 + dj;
                s_img[row * RS1 + cp * 4 + cch] = f2bf(acc[r]);
            }
        }
    }
    // zero pad-channel 3, row pads (cols 128..135), and LDS tails: no uninit reads ever
    for (int p = tid; p < 1024; p += 256)
        s_img[(p >> 5) * RS1 + (p & 31) * 4 + 3] = 0;
    if (tid < 256) s_img[(tid >> 3) * RS1 + 128 + (tid & 7)] = 0;
    if (tid < 64) s_img[32 * RS1 + tid] = 0;
    if (tid < 64) s_h1[14 * RS2 + tid] = 0;
    __syncthreads();

    // ---------------- Phase 2: conv1+pool+relu via MFMA -> s_h1 (HWC12 bf16) ----------------
    // M = 784 conv pixels in quad order; 49 M-tiles, 5 K-steps (ky), N=10 (1 tile).
    {
        Frag bc1[5];                              // resident: phase-2 peak ~45 VGPR
        #pragma unroll
        for (int f = 0; f < 5; ++f)
            bc1[f].v = *(const bf16x8*)(ws + (6 + f) * 512 + lane * 8);
        const float bias1 = b1[col16 < 10 ? col16 : 0];

        for (int t = wave; t < 49; t += 4) {
            const int q = 4 * t + (col16 >> 2), sub = col16 & 3;   // A row m = col16
            const int oi = q / 14, oj = q % 14;
            const int ci = 2 * oi + (sub >> 1), cj = 2 * oj + (sub & 1);
            const int base = ci * RS1 + cj * 4 + 4 * grp;
            f32x4 acc = {0.f, 0.f, 0.f, 0.f};
            #pragma unroll
            for (int ky = 0; ky < 5; ++ky) {
                Frag a;
                a.h[0] = *(const short4*)&s_img[base + ky * RS1];
                a.h[1] = *(const short4*)&s_img[base + ky * RS1 + 16];
                acc = MFMA(a.v, bc1[ky].v, acc);
            }
            const int qo = 4 * t + grp;          // C rows 4*grp..+3 = one pool quad
            if (col16 < 12) {
                const float pm = fmaxf(fmaxf(acc[0], acc[1]), fmaxf(acc[2], acc[3]));
                const float val = fmaxf(pm + bias1, 0.f);
                s_h1[(qo / 14) * RS2 + (qo % 14) * 12 + col16] =
                    (col16 < 10) ? f2bf(val) : (unsigned short)0;
            }
        }
    }
    __syncthreads();

    // ---------------- Phase 3: conv2+pool+relu via MFMA -> s_h2 (f32, flatten order) ----------------
    // M = 100 conv pixels in quad order (25 quads -> 7 M-tiles); 10 K-steps; N = 2 tiles.
    // B-frags from LDS (staged once): 16B-stride ds_read_b128, conflict-free.
    {
        const int oc1 = 16 + col16;
        const float bias20 = b2[col16];                    // col16 <= 15 < 20
        const float bias21 = b2[oc1 < 20 ? oc1 : 0];

        for (int t = wave; t < 7; t += 4) {
            int q = 4 * t + (col16 >> 2); if (q > 24) q = 24;   // clamp garbage rows in-bounds
            const int sub = col16 & 3;
            const int oi = q / 5, oj = q % 5;
            const int ci = 2 * oi + (sub >> 1), cj = 2 * oj + (sub & 1);
            const int base = ci * RS2 + cj * 12 + 4 * grp;
            f32x4 acc0 = {0.f, 0.f, 0.f, 0.f}, acc1 = {0.f, 0.f, 0.f, 0.f};
            #pragma unroll
            for (int ky = 0; ky < 5; ++ky) {
                #pragma unroll
                for (int s = 0; s < 2; ++s) {
                    Frag a, bb0, bb1;
                    a.h[0] = *(const short4*)&s_h1[base + ky * RS2 + 32 * s];
                    a.h[1] = *(const short4*)&s_h1[base + ky * RS2 + 32 * s + 16];
                    bb0.v = *(const bf16x8*)(s_b2 + (ky * 2 + s) * 512 + lane * 8);
                    bb1.v = *(const bf16x8*)(s_b2 + (10 + ky * 2 + s) * 512 + lane * 8);
                    acc0 = MFMA(a.v, bb0.v, acc0);
                    acc1 = MFMA(a.v, bb1.v, acc1);
                }
            }
            const int qo = 4 * t + grp;
            if (qo < 25) {
                const float p0 = fmaxf(fmaxf(acc0[0], acc0[1]), fmaxf(acc0[2], acc0[3]));
                s_h2[col16 * 25 + qo] = fmaxf(p0 + bias20, 0.f);
                if (oc1 < 20) {
                    const float p1 = fmaxf(fmaxf(acc1[0], acc1[1]), fmaxf(acc1[2], acc1[3]));
                    s_h2[oc1 * 25 + qo] = fmaxf(p1 + bias21, 0.f);
                }
            }
        }
    }
    __syncthreads();

    // ---------------- Phase 4: fc1 (500->50, bf16 weights) split 5-way + relu ----------------
    if (tid < 250) {
        const int oc = tid / 5, part = tid % 5;
        const unsigned* wr = (const unsigned*)(ws + 16384 + oc * 500 + part * 100);
        const float* hp = s_h2 + part * 100;
        float a = 0.f;
        #pragma unroll
        for (int i = 0; i < 25; ++i) {
            const float4 hv = *(const float4*)(hp + 4 * i);
            const unsigned ua = wr[2 * i], ub = wr[2 * i + 1];
            a += __uint_as_float(ua << 16)          * hv.x
               + __uint_as_float(ua & 0xffff0000u) * hv.y
               + __uint_as_float(ub << 16)          * hv.z
               + __uint_as_float(ub & 0xffff0000u) * hv.w;
        }
        s_part[tid] = a;
    }
    __syncthreads();
    if (tid < 50) {
        float a = fb1[tid];
        #pragma unroll
        for (int j = 0; j < 5; ++j) a += s_part[tid * 5 + j];
        s_f1[tid] = fmaxf(a, 0.f);
    }
    __syncthreads();

    // ---------------- Phase 5: fc2 (50->10) ----------------
    if (tid < 10) {
        const float* wr = fw2 + tid * 50;
        float a = fb2[tid];
        for (int k = 0; k < 50; ++k) a += s_f1[k] * wr[k];
        s_lg[tid] = a;
    }
    __syncthreads();

    // ---------------- Phase 6: log_softmax ----------------
    if (tid < 10) {
        float m = s_lg[0];
        for (int k = 1; k < 10; ++k) m = fmaxf(m, s_lg[k]);
        float s = 0.f;
        for (int k = 0; k < 10; ++k) s += expf(s_lg[k] - m);
        out[(size_t)b * 10 + tid] = s_lg[tid] - m - logf(s);
    }
}

extern "C" void kernel_launch(void* const* d_in, const int* in_sizes, int n_in,
                              void* d_out, int out_size, void* d_ws, size_t ws_size,
                              hipStream_t stream) {
    const float* x   = (const float*)d_in[0];
    const float* W   = (const float*)d_in[1];
    const float* w1  = (const float*)d_in[2];
    const float* b1  = (const float*)d_in[3];
    const float* w2  = (const float*)d_in[4];
    const float* b2  = (const float*)d_in[5];
    const float* fw1 = (const float*)d_in[6];
    const float* fb1 = (const float*)d_in[7];
    const float* fw2 = (const float*)d_in[8];
    const float* fb2 = (const float*)d_in[9];
    float* o = (float*)d_out;
    unsigned short* wsp = (unsigned short*)d_ws;

    const int B = in_sizes[0] / 3072;
    prepack<<<dim3(31), dim3(64), 0, stream>>>(W, w1, w2, wsp);
    pack_fc1<<<dim3(49), dim3(256), 0, stream>>>(fw1, wsp);
    fused_net<<<dim3(B), dim3(256), 0, stream>>>(x, wsp, b1, b2, fb1, fw2, fb2, o);
}

// Round 10
// 135.045 us; speedup vs baseline: 1.8325x; 1.0049x over previous
//
#include <hip/hip_runtime.h>
#include <math.h>

// Fused net, round 10: occupancy via LDS footprint + fewer LDS reads.
//  (a) s_b2 (conv2 B-frags, 20KB) re-staged AFTER phase 2 into s_img's space
//      (s_img dead post-phase-2) -> LDS 37.9KB -> ~28.7KB -> 5 blocks/CU.
//  (b) s_h2/s_part/s_f1/s_lg aliased into the pool tail.
//  (c) phase 3 loop swap: (ky,s) outer, t inner -> B-frags read once per K-step
//      (160 -> 80 wave-reads/block), acc[2][2] static-indexed (rule #20 safe).
//  No launch-bounds min-waves clause (rounds 2/6/8: allocator footgun).

typedef __attribute__((ext_vector_type(8))) short bf16x8;
typedef __attribute__((ext_vector_type(4))) float f32x4;

union Frag { short4 h[2]; bf16x8 v; };

static __device__ __forceinline__ unsigned short f2bf(float f) {
    union { float f; unsigned u; } v; v.f = f;
    unsigned r = v.u + 0x7FFFu + ((v.u >> 16) & 1u);   // RNE
    return (unsigned short)(r >> 16);
}

#define MFMA(a, b, c) __builtin_amdgcn_mfma_f32_16x16x32_bf16((a), (b), (c), 0, 0, 0)

// ---------------- B-fragment prepack: 31 frags x 64 lanes x 8 bf16 ----------------
// fid 0..5  : linear  B[k][j]=W[j][k], fid=ks*3+nt (K=48 -> 2 steps, N=48 -> 3 tiles)
// fid 6..10 : conv1   ky=fid-6; window elem e=kx*4+icp (pixel stride 4)
// fid 11..30: conv2   fid-11 = nt*10+ky*2+s; window elem idx=32s+kap, idx=kx*12+icp
__global__ __launch_bounds__(64)
void prepack(const float* __restrict__ W, const float* __restrict__ w1,
             const float* __restrict__ w2, unsigned short* __restrict__ ws) {
    const int fid = blockIdx.x;
    const int lane = threadIdx.x;
    const int col = lane & 15, grp = lane >> 4;
    unsigned short tmp[8];
    #pragma unroll
    for (int e = 0; e < 8; ++e) {
        const int kap = 16 * (e >> 2) + 4 * grp + (e & 3);   // 0..31
        float v = 0.f;
        if (fid < 6) {
            const int ks = fid / 3, nt = fid % 3;
            const int k = 32 * ks + kap, j = 16 * nt + col;
            if (k < 48) v = W[j * 48 + k];
        } else if (fid < 11) {
            const int ky = fid - 6;
            const int kx = kap >> 2, icp = kap & 3;
            if (kx < 5 && icp < 3 && col < 10)
                v = w1[col * 75 + icp * 25 + ky * 5 + kx];
        } else {
            const int r = fid - 11, nt = r / 10, ky = (r % 10) >> 1, s = r & 1;
            const int idx = 32 * s + kap;
            const int kx = idx / 12, icp = idx % 12, oc = 16 * nt + col;
            if (kx < 5 && icp < 10 && oc < 20)
                v = w2[oc * 250 + icp * 25 + ky * 5 + kx];
        }
        tmp[e] = f2bf(v);
    }
    Frag f;
    f.h[0] = make_short4((short)tmp[0], (short)tmp[1], (short)tmp[2], (short)tmp[3]);
    f.h[1] = make_short4((short)tmp[4], (short)tmp[5], (short)tmp[6], (short)tmp[7]);
    *(bf16x8*)(ws + fid * 512 + lane * 8) = f.v;
}

// ---------------- fc1 weight pack: fw1 [50,500] f32 -> bf16 pairs at ws+16384 ----------------
__global__ __launch_bounds__(256)
void pack_fc1(const float* __restrict__ fw1, unsigned short* __restrict__ ws) {
    const int i = blockIdx.x * 256 + threadIdx.x;   // uint index, 12500 total
    if (i < 12500) {
        const unsigned lo = f2bf(fw1[2 * i]);
        const unsigned hi = f2bf(fw1[2 * i + 1]);
        ((unsigned*)(ws + 16384))[i] = lo | (hi << 16);
    }
}

// ---------------- main fused kernel: one block (256 thr) per image ----------------
#define RS1 136   // s_img row stride (elems): 32 cols * 4ch + 8 pad
#define RS2 168   // s_h1 row stride (elems): 14 cols * 12ch

__global__ __launch_bounds__(256)
void fused_net(const float* __restrict__ x,    // [B,32,32,3] NHWC f32
               const unsigned short* __restrict__ ws, // prepacked B-frags + bf16 fc1 w
               const float* __restrict__ b1,   // [10]
               const float* __restrict__ b2,   // [20]
               const float* __restrict__ fb1,  // [50]
               const float* __restrict__ fw2,  // [10,50]
               const float* __restrict__ fb2,  // [10]
               float* __restrict__ out)        // [B,10]
{
    const int b    = blockIdx.x;
    const int tid  = threadIdx.x;
    const int wave = __builtin_amdgcn_readfirstlane(tid >> 6);
    const int lane = tid & 63;
    const int col16 = lane & 15, grp = lane >> 4;

    // Pool: [0,10240) ushort = s_b2 (phase>=3) / s_img lives in [0,4416) (phases 1-2)
    //       [10240,...)      = aux floats: s_h2(500+12 pad), s_part(256), s_f1(56), s_lg(16)
    __shared__ __align__(16) unsigned short s_pool[10240 + 1696];
    __shared__ __align__(16) unsigned short s_h1[14 * RS2 + 64];   // HWC12 bf16 + zeroed tail
    unsigned short* s_img = s_pool;
    unsigned short* s_b2  = s_pool;
    float* s_h2   = (float*)(s_pool + 10240);   // 512 floats (500 used)
    float* s_part = s_h2 + 512;                  // 256
    float* s_f1   = s_part + 256;                // 56 -> 64
    float* s_lg   = s_f1 + 64;                   // 16

    // ---------------- Phase 1: linear via MFMA -> s_img (HWC4 bf16) ----------------
    {
        const int blkA = 16 * wave + col16;
        const float* xb = x + (size_t)b * 3072 + (blkA >> 3) * 384 + (blkA & 7) * 12;
        const int k0 = 4 * grp,      o0 = (k0 / 12) * 96 + (k0 % 12);
        const int k1 = 16 + 4 * grp, o1 = (k1 / 12) * 96 + (k1 % 12);
        const int k2 = 32 + 4 * grp, o2 = (k2 / 12) * 96 + (k2 % 12);
        const float4 fa = *(const float4*)(xb + o0);
        const float4 fb = *(const float4*)(xb + o1);
        const float4 fc = *(const float4*)(xb + o2);
        Frag a0, a1;
        a0.h[0] = make_short4((short)f2bf(fa.x), (short)f2bf(fa.y), (short)f2bf(fa.z), (short)f2bf(fa.w));
        a0.h[1] = make_short4((short)f2bf(fb.x), (short)f2bf(fb.y), (short)f2bf(fb.z), (short)f2bf(fb.w));
        a1.h[0] = make_short4((short)f2bf(fc.x), (short)f2bf(fc.y), (short)f2bf(fc.z), (short)f2bf(fc.w));
        a1.h[1] = make_short4(0, 0, 0, 0);        // k>=48 pad: zero (also avoids OOB x reads)

        #pragma unroll
        for (int nt = 0; nt < 3; ++nt) {
            Frag bl0, bl1;                        // streamed from L2 (one-shot use)
            bl0.v = *(const bf16x8*)(ws + nt * 512 + lane * 8);
            bl1.v = *(const bf16x8*)(ws + (3 + nt) * 512 + lane * 8);
            f32x4 acc = {0.f, 0.f, 0.f, 0.f};
            acc = MFMA(a0.v, bl0.v, acc);
            acc = MFMA(a1.v, bl1.v, acc);
            const int j = 16 * nt + col16;                 // output k' index
            const int di = j / 12, dj = (j % 12) / 3, cch = j % 3;
            #pragma unroll
            for (int r = 0; r < 4; ++r) {
                const int blk = 16 * wave + 4 * grp + r;   // C row = block id
                const int row = (blk >> 3) * 4 + di, cp = (blk & 7) * 4 + dj;
                s_img[row * RS1 + cp * 4 + cch] = f2bf(acc[r]);
            }
        }
    }
    // zero pad-channel 3, row pads (cols 128..135), and LDS tails: no uninit reads ever
    for (int p = tid; p < 1024; p += 256)
        s_img[(p >> 5) * RS1 + (p & 31) * 4 + 3] = 0;
    if (tid < 256) s_img[(tid >> 3) * RS1 + 128 + (tid & 7)] = 0;
    if (tid < 64) s_img[32 * RS1 + tid] = 0;
    if (tid < 64) s_h1[14 * RS2 + tid] = 0;
    __syncthreads();

    // ---------------- Phase 2: conv1+pool+relu via MFMA -> s_h1 (HWC12 bf16) ----------------
    // M = 784 conv pixels in quad order; 49 M-tiles, 5 K-steps (ky), N=10 (1 tile).
    {
        Frag bc1[5];                              // resident across t-loop
        #pragma unroll
        for (int f = 0; f < 5; ++f)
            bc1[f].v = *(const bf16x8*)(ws + (6 + f) * 512 + lane * 8);
        const float bias1 = b1[col16 < 10 ? col16 : 0];

        for (int t = wave; t < 49; t += 4) {
            const int q = 4 * t + (col16 >> 2), sub = col16 & 3;   // A row m = col16
            const int oi = q / 14, oj = q % 14;
            const int ci = 2 * oi + (sub >> 1), cj = 2 * oj + (sub & 1);
            const int base = ci * RS1 + cj * 4 + 4 * grp;
            f32x4 acc = {0.f, 0.f, 0.f, 0.f};
            #pragma unroll
            for (int ky = 0; ky < 5; ++ky) {
                Frag a;
                a.h[0] = *(const short4*)&s_img[base + ky * RS1];
                a.h[1] = *(const short4*)&s_img[base + ky * RS1 + 16];
                acc = MFMA(a.v, bc1[ky].v, acc);
            }
            const int qo = 4 * t + grp;          // C rows 4*grp..+3 = one pool quad
            if (col16 < 12) {
                const float pm = fmaxf(fmaxf(acc[0], acc[1]), fmaxf(acc[2], acc[3]));
                const float val = fmaxf(pm + bias1, 0.f);
                s_h1[(qo / 14) * RS2 + (qo % 14) * 12 + col16] =
                    (col16 < 10) ? f2bf(val) : (unsigned short)0;
            }
        }
    }
    __syncthreads();

    // ---- re-stage conv2 B-frags (20KB) into s_pool (s_img now dead) ----
    {
        const uint4* src = (const uint4*)(ws + 11 * 512);   // frags 11..30 contiguous
        uint4* dst = (uint4*)s_b2;
        #pragma unroll
        for (int i = 0; i < 5; ++i)
            dst[tid + 256 * i] = src[tid + 256 * i];
    }
    __syncthreads();

    // ---------------- Phase 3: conv2+pool+relu via MFMA -> s_h2 (f32, flatten order) ----------------
    // (ky,s) outer, t inner: each B-frag pair read once per K-step. acc[2][2] static-indexed.
    {
        const int oc1 = 16 + col16;
        const float bias20 = b2[col16];                    // col16 <= 15 < 20
        const float bias21 = b2[oc1 < 20 ? oc1 : 0];

        int baseA[2];
        #pragma unroll
        for (int tt = 0; tt < 2; ++tt) {
            const int t = wave + 4 * tt;                   // t in {wave, wave+4}
            int q = 4 * t + (col16 >> 2); if (q > 24) q = 24;   // clamp keeps reads in-bounds
            const int sub = col16 & 3;
            const int oi = q / 5, oj = q % 5;
            const int ci = 2 * oi + (sub >> 1), cj = 2 * oj + (sub & 1);
            baseA[tt] = ci * RS2 + cj * 12 + 4 * grp;
        }

        f32x4 accA0 = {0.f,0.f,0.f,0.f}, accA1 = {0.f,0.f,0.f,0.f};   // tile tt=0: N-tile 0/1
        f32x4 accB0 = {0.f,0.f,0.f,0.f}, accB1 = {0.f,0.f,0.f,0.f};   // tile tt=1
        #pragma unroll
        for (int ky = 0; ky < 5; ++ky) {
            #pragma unroll
            for (int s = 0; s < 2; ++s) {
                Frag bb0, bb1;
                bb0.v = *(const bf16x8*)(s_b2 + (ky * 2 + s) * 512 + lane * 8);
                bb1.v = *(const bf16x8*)(s_b2 + (10 + ky * 2 + s) * 512 + lane * 8);
                Frag a0, a1;
                a0.h[0] = *(const short4*)&s_h1[baseA[0] + ky * RS2 + 32 * s];
                a0.h[1] = *(const short4*)&s_h1[baseA[0] + ky * RS2 + 32 * s + 16];
                a1.h[0] = *(const short4*)&s_h1[baseA[1] + ky * RS2 + 32 * s];
                a1.h[1] = *(const short4*)&s_h1[baseA[1] + ky * RS2 + 32 * s + 16];
                accA0 = MFMA(a0.v, bb0.v, accA0);
                accA1 = MFMA(a0.v, bb1.v, accA1);
                accB0 = MFMA(a1.v, bb0.v, accB0);
                accB1 = MFMA(a1.v, bb1.v, accB1);
            }
        }
        #pragma unroll
        for (int tt = 0; tt < 2; ++tt) {
            const int t = wave + 4 * tt;
            if (t < 7) {
                const f32x4 c0 = tt ? accB0 : accA0;
                const f32x4 c1 = tt ? accB1 : accA1;
                const int qo = 4 * t + grp;
                if (qo < 25) {
                    const float p0 = fmaxf(fmaxf(c0[0], c0[1]), fmaxf(c0[2], c0[3]));
                    s_h2[col16 * 25 + qo] = fmaxf(p0 + bias20, 0.f);
                    if (oc1 < 20) {
                        const float p1 = fmaxf(fmaxf(c1[0], c1[1]), fmaxf(c1[2], c1[3]));
                        s_h2[oc1 * 25 + qo] = fmaxf(p1 + bias21, 0.f);
                    }
                }
            }
        }
    }
    __syncthreads();

    // ---------------- Phase 4: fc1 (500->50, bf16 weights) split 5-way + relu ----------------
    if (tid < 250) {
        const int oc = tid / 5, part = tid % 5;
        const unsigned* wr = (const unsigned*)(ws + 16384 + oc * 500 + part * 100);
        const float* hp = s_h2 + part * 100;
        float a = 0.f;
        #pragma unroll
        for (int i = 0; i < 25; ++i) {
            const float4 hv = *(const float4*)(hp + 4 * i);
            const unsigned ua = wr[2 * i], ub = wr[2 * i + 1];
            a += __uint_as_float(ua << 16)          * hv.x
               + __uint_as_float(ua & 0xffff0000u) * hv.y
               + __uint_as_float(ub << 16)          * hv.z
               + __uint_as_float(ub & 0xffff0000u) * hv.w;
        }
        s_part[tid] = a;
    }
    __syncthreads();
    if (tid < 50) {
        float a = fb1[tid];
        #pragma unroll
        for (int j = 0; j < 5; ++j) a += s_part[tid * 5 + j];
        s_f1[tid] = fmaxf(a, 0.f);
    }
    __syncthreads();

    // ---------------- Phase 5: fc2 (50->10) ----------------
    if (tid < 10) {
        const float* wr = fw2 + tid * 50;
        float a = fb2[tid];
        for (int k = 0; k < 50; ++k) a += s_f1[k] * wr[k];
        s_lg[tid] = a;
    }
    __syncthreads();

    // ---------------- Phase 6: log_softmax ----------------
    if (tid < 10) {
        float m = s_lg[0];
        for (int k = 1; k < 10; ++k) m = fmaxf(m, s_lg[k]);
        float s = 0.f;
        for (int k = 0; k < 10; ++k) s += expf(s_lg[k] - m);
        out[(size_t)b * 10 + tid] = s_lg[tid] - m - logf(s);
    }
}

extern "C" void kernel_launch(void* const* d_in, const int* in_sizes, int n_in,
                              void* d_out, int out_size, void* d_ws, size_t ws_size,
                              hipStream_t stream) {
    const float* x   = (const float*)d_in[0];
    const float* W   = (const float*)d_in[1];
    const float* w1  = (const float*)d_in[2];
    const float* b1  = (const float*)d_in[3];
    const float* w2  = (const float*)d_in[4];
    const float* b2  = (const float*)d_in[5];
    const float* fw1 = (const float*)d_in[6];
    const float* fb1 = (const float*)d_in[7];
    const float* fw2 = (const float*)d_in[8];
    const float* fb2 = (const float*)d_in[9];
    float* o = (float*)d_out;
    unsigned short* wsp = (unsigned short*)d_ws;

    const int B = in_sizes[0] / 3072;
    prepack<<<dim3(31), dim3(64), 0, stream>>>(W, w1, w2, wsp);
    pack_fc1<<<dim3(49), dim3(256), 0, stream>>>(fw1, wsp);
    fused_net<<<dim3(B), dim3(256), 0, stream>>>(x, wsp, b1, b2, fb1, fw2, fb2, o);
}

// Round 11
// 119.188 us; speedup vs baseline: 2.0763x; 1.1330x over previous
//
#include <hip/hip_runtime.h>
#include <math.h>

// Fused net, round 11: TWO images per block (512 threads, 8 waves).
// waves 0-3 -> image A, waves 4-7 -> image B (wv = wave&3 runs the old 4-wave code).
// Buys: 8 waves per ~37KB LDS block (more latency hiding), and per-image fixed
// costs halve (B2 restage, pad zeroing, barriers, phase-1/2 B-frag + fc1 L2 reads
// amortized over 2 images). Per-wave code identical -> VGPR unchanged (~60).
// No launch-bounds min-waves clause (rounds 2/6/8: allocator footgun).

typedef __attribute__((ext_vector_type(8))) short bf16x8;
typedef __attribute__((ext_vector_type(4))) float f32x4;

union Frag { short4 h[2]; bf16x8 v; };

static __device__ __forceinline__ unsigned short f2bf(float f) {
    union { float f; unsigned u; } v; v.f = f;
    unsigned r = v.u + 0x7FFFu + ((v.u >> 16) & 1u);   // RNE
    return (unsigned short)(r >> 16);
}

#define MFMA(a, b, c) __builtin_amdgcn_mfma_f32_16x16x32_bf16((a), (b), (c), 0, 0, 0)

// ---------------- B-fragment prepack: 31 frags x 64 lanes x 8 bf16 ----------------
// fid 0..5  : linear  B[k][j]=W[j][k], fid=ks*3+nt (K=48 -> 2 steps, N=48 -> 3 tiles)
// fid 6..10 : conv1   ky=fid-6; window elem e=kx*4+icp (pixel stride 4)
// fid 11..30: conv2   fid-11 = nt*10+ky*2+s; window elem idx=32s+kap, idx=kx*12+icp
__global__ __launch_bounds__(64)
void prepack(const float* __restrict__ W, const float* __restrict__ w1,
             const float* __restrict__ w2, unsigned short* __restrict__ ws) {
    const int fid = blockIdx.x;
    const int lane = threadIdx.x;
    const int col = lane & 15, grp = lane >> 4;
    unsigned short tmp[8];
    #pragma unroll
    for (int e = 0; e < 8; ++e) {
        const int kap = 16 * (e >> 2) + 4 * grp + (e & 3);   // 0..31
        float v = 0.f;
        if (fid < 6) {
            const int ks = fid / 3, nt = fid % 3;
            const int k = 32 * ks + kap, j = 16 * nt + col;
            if (k < 48) v = W[j * 48 + k];
        } else if (fid < 11) {
            const int ky = fid - 6;
            const int kx = kap >> 2, icp = kap & 3;
            if (kx < 5 && icp < 3 && col < 10)
                v = w1[col * 75 + icp * 25 + ky * 5 + kx];
        } else {
            const int r = fid - 11, nt = r / 10, ky = (r % 10) >> 1, s = r & 1;
            const int idx = 32 * s + kap;
            const int kx = idx / 12, icp = idx % 12, oc = 16 * nt + col;
            if (kx < 5 && icp < 10 && oc < 20)
                v = w2[oc * 250 + icp * 25 + ky * 5 + kx];
        }
        tmp[e] = f2bf(v);
    }
    Frag f;
    f.h[0] = make_short4((short)tmp[0], (short)tmp[1], (short)tmp[2], (short)tmp[3]);
    f.h[1] = make_short4((short)tmp[4], (short)tmp[5], (short)tmp[6], (short)tmp[7]);
    *(bf16x8*)(ws + fid * 512 + lane * 8) = f.v;
}

// ---------------- fc1 weight pack: fw1 [50,500] f32 -> bf16 pairs at ws+16384 ----------------
__global__ __launch_bounds__(256)
void pack_fc1(const float* __restrict__ fw1, unsigned short* __restrict__ ws) {
    const int i = blockIdx.x * 256 + threadIdx.x;   // uint index, 12500 total
    if (i < 12500) {
        const unsigned lo = f2bf(fw1[2 * i]);
        const unsigned hi = f2bf(fw1[2 * i + 1]);
        ((unsigned*)(ws + 16384))[i] = lo | (hi << 16);
    }
}

// ---------------- main fused kernel: one block (512 thr) per TWO images ----------------
#define RS1 136              // s_img row stride (elems): 32 cols * 4ch + 8 pad
#define IMG_SZ 4416          // 32*RS1 + 64 tail (ushorts, 8-divisible)
#define RS2 168              // s_h1 row stride (elems): 14 cols * 12ch
#define H1_SZ 2416           // 14*RS2 + 64 tail
#define AUXF 848             // per-image aux floats: h2 512 | part 256 | f1 64 | lg 16

__global__ __launch_bounds__(512)
void fused_net(const float* __restrict__ x,    // [B,32,32,3] NHWC f32
               const unsigned short* __restrict__ ws, // prepacked B-frags + bf16 fc1 w
               const float* __restrict__ b1,   // [10]
               const float* __restrict__ b2,   // [20]
               const float* __restrict__ fb1,  // [50]
               const float* __restrict__ fw2,  // [10,50]
               const float* __restrict__ fb2,  // [10]
               float* __restrict__ out)        // [B,10]
{
    const int tid  = threadIdx.x;
    const int wave = __builtin_amdgcn_readfirstlane(tid >> 6);   // 0..7
    const int img  = wave >> 2;                                  // 0..1
    const int wv   = wave & 3;                                   // old 4-wave id
    const int lane = tid & 63;
    const int col16 = lane & 15, grp = lane >> 4;

    // s_pool: phases 1-2 = imgA[0,4416) imgB[4416,8832); phase >=3 = s_b2[0,10240)
    __shared__ __align__(16) unsigned short s_pool[10240];
    __shared__ __align__(16) unsigned short s_h1[2 * H1_SZ];
    __shared__ __align__(16) float s_aux[2 * AUXF];

    unsigned short* s_img = s_pool + img * IMG_SZ;
    unsigned short* s_h1i = s_h1 + img * H1_SZ;
    unsigned short* s_b2  = s_pool;
    float* aux    = s_aux + img * AUXF;
    float* s_h2   = aux;            // 512 (500 used)
    float* s_lg   = aux + 832;      // 16

    const size_t bb = (size_t)(2 * blockIdx.x + img);   // batch index of this wave's image

    // ---------------- Phase 1: linear via MFMA -> s_img (HWC4 bf16) ----------------
    {
        const int blkA = 16 * wv + col16;
        const float* xb = x + bb * 3072 + (blkA >> 3) * 384 + (blkA & 7) * 12;
        const int k0 = 4 * grp,      o0 = (k0 / 12) * 96 + (k0 % 12);
        const int k1 = 16 + 4 * grp, o1 = (k1 / 12) * 96 + (k1 % 12);
        const int k2 = 32 + 4 * grp, o2 = (k2 / 12) * 96 + (k2 % 12);
        const float4 fa = *(const float4*)(xb + o0);
        const float4 fb = *(const float4*)(xb + o1);
        const float4 fc = *(const float4*)(xb + o2);
        Frag a0, a1;
        a0.h[0] = make_short4((short)f2bf(fa.x), (short)f2bf(fa.y), (short)f2bf(fa.z), (short)f2bf(fa.w));
        a0.h[1] = make_short4((short)f2bf(fb.x), (short)f2bf(fb.y), (short)f2bf(fb.z), (short)f2bf(fb.w));
        a1.h[0] = make_short4((short)f2bf(fc.x), (short)f2bf(fc.y), (short)f2bf(fc.z), (short)f2bf(fc.w));
        a1.h[1] = make_short4(0, 0, 0, 0);        // k>=48 pad: zero (also avoids OOB x reads)

        #pragma unroll
        for (int nt = 0; nt < 3; ++nt) {
            Frag bl0, bl1;                        // streamed from L2 (shared by both images)
            bl0.v = *(const bf16x8*)(ws + nt * 512 + lane * 8);
            bl1.v = *(const bf16x8*)(ws + (3 + nt) * 512 + lane * 8);
            f32x4 acc = {0.f, 0.f, 0.f, 0.f};
            acc = MFMA(a0.v, bl0.v, acc);
            acc = MFMA(a1.v, bl1.v, acc);
            const int j = 16 * nt + col16;                 // output k' index
            const int di = j / 12, dj = (j % 12) / 3, cch = j % 3;
            #pragma unroll
            for (int r = 0; r < 4; ++r) {
                const int blk = 16 * wv + 4 * grp + r;     // C row = block id
                const int row = (blk >> 3) * 4 + di, cp = (blk & 7) * 4 + dj;
                s_img[row * RS1 + cp * 4 + cch] = f2bf(acc[r]);
            }
        }
    }
    // zero pad-channel 3, row pads (cols 128..135), and LDS tails for BOTH images
    for (int p = tid; p < 2048; p += 512) {
        unsigned short* si = s_pool + (p >> 10) * IMG_SZ;
        const int q = p & 1023;
        si[(q >> 5) * RS1 + (q & 31) * 4 + 3] = 0;
    }
    {
        unsigned short* si = s_pool + (tid >> 8) * IMG_SZ;
        const int r = tid & 255;
        si[(r >> 3) * RS1 + 128 + (r & 7)] = 0;
    }
    if (tid < 128) s_pool[(tid >> 6) * IMG_SZ + 32 * RS1 + (tid & 63)] = 0;
    if (tid < 128) s_h1[(tid >> 6) * H1_SZ + 14 * RS2 + (tid & 63)] = 0;
    __syncthreads();

    // ---------------- Phase 2: conv1+pool+relu via MFMA -> s_h1 (HWC12 bf16) ----------------
    {
        Frag bc1[5];                              // resident across t-loop
        #pragma unroll
        for (int f = 0; f < 5; ++f)
            bc1[f].v = *(const bf16x8*)(ws + (6 + f) * 512 + lane * 8);
        const float bias1 = b1[col16 < 10 ? col16 : 0];

        for (int t = wv; t < 49; t += 4) {
            const int q = 4 * t + (col16 >> 2), sub = col16 & 3;   // A row m = col16
            const int oi = q / 14, oj = q % 14;
            const int ci = 2 * oi + (sub >> 1), cj = 2 * oj + (sub & 1);
            const int base = ci * RS1 + cj * 4 + 4 * grp;
            f32x4 acc = {0.f, 0.f, 0.f, 0.f};
            #pragma unroll
            for (int ky = 0; ky < 5; ++ky) {
                Frag a;
                a.h[0] = *(const short4*)&s_img[base + ky * RS1];
                a.h[1] = *(const short4*)&s_img[base + ky * RS1 + 16];
                acc = MFMA(a.v, bc1[ky].v, acc);
            }
            const int qo = 4 * t + grp;          // C rows 4*grp..+3 = one pool quad
            if (col16 < 12) {
                const float pm = fmaxf(fmaxf(acc[0], acc[1]), fmaxf(acc[2], acc[3]));
                const float val = fmaxf(pm + bias1, 0.f);
                s_h1i[(qo / 14) * RS2 + (qo % 14) * 12 + col16] =
                    (col16 < 10) ? f2bf(val) : (unsigned short)0;
            }
        }
    }
    __syncthreads();

    // ---- re-stage conv2 B-frags (20KB) into s_pool (both s_img now dead) ----
    {
        const uint4* src = (const uint4*)(ws + 11 * 512);   // frags 11..30, 1280 uint4
        uint4* dst = (uint4*)s_pool;
        dst[tid]       = src[tid];
        dst[tid + 512] = src[tid + 512];
        if (tid < 256) dst[tid + 1024] = src[tid + 1024];
    }
    __syncthreads();

    // ---------------- Phase 3: conv2+pool+relu via MFMA -> s_h2 (f32, flatten order) ----------------
    // (ky,s) outer, t inner: each B-frag pair read once per K-step. acc static-indexed.
    {
        const int oc1 = 16 + col16;
        const float bias20 = b2[col16];                    // col16 <= 15 < 20
        const float bias21 = b2[oc1 < 20 ? oc1 : 0];

        int baseA[2];
        #pragma unroll
        for (int tt = 0; tt < 2; ++tt) {
            const int t = wv + 4 * tt;                     // t in {wv, wv+4}
            int q = 4 * t + (col16 >> 2); if (q > 24) q = 24;   // clamp keeps reads in-bounds
            const int sub = col16 & 3;
            const int oi = q / 5, oj = q % 5;
            const int ci = 2 * oi + (sub >> 1), cj = 2 * oj + (sub & 1);
            baseA[tt] = ci * RS2 + cj * 12 + 4 * grp;
        }

        f32x4 accA0 = {0.f,0.f,0.f,0.f}, accA1 = {0.f,0.f,0.f,0.f};   // tile tt=0: N-tile 0/1
        f32x4 accB0 = {0.f,0.f,0.f,0.f}, accB1 = {0.f,0.f,0.f,0.f};   // tile tt=1
        #pragma unroll
        for (int ky = 0; ky < 5; ++ky) {
            #pragma unroll
            for (int s = 0; s < 2; ++s) {
                Frag bb0, bb1;
                bb0.v = *(const bf16x8*)(s_b2 + (ky * 2 + s) * 512 + lane * 8);
                bb1.v = *(const bf16x8*)(s_b2 + (10 + ky * 2 + s) * 512 + lane * 8);
                Frag a0, a1;
                a0.h[0] = *(const short4*)&s_h1i[baseA[0] + ky * RS2 + 32 * s];
                a0.h[1] = *(const short4*)&s_h1i[baseA[0] + ky * RS2 + 32 * s + 16];
                a1.h[0] = *(const short4*)&s_h1i[baseA[1] + ky * RS2 + 32 * s];
                a1.h[1] = *(const short4*)&s_h1i[baseA[1] + ky * RS2 + 32 * s + 16];
                accA0 = MFMA(a0.v, bb0.v, accA0);
                accA1 = MFMA(a0.v, bb1.v, accA1);
                accB0 = MFMA(a1.v, bb0.v, accB0);
                accB1 = MFMA(a1.v, bb1.v, accB1);
            }
        }
        #pragma unroll
        for (int tt = 0; tt < 2; ++tt) {
            const int t = wv + 4 * tt;
            if (t < 7) {
                const f32x4 c0 = tt ? accB0 : accA0;
                const f32x4 c1 = tt ? accB1 : accA1;
                const int qo = 4 * t + grp;
                if (qo < 25) {
                    const float p0 = fmaxf(fmaxf(c0[0], c0[1]), fmaxf(c0[2], c0[3]));
                    s_h2[col16 * 25 + qo] = fmaxf(p0 + bias20, 0.f);
                    if (oc1 < 20) {
                        const float p1 = fmaxf(fmaxf(c1[0], c1[1]), fmaxf(c1[2], c1[3]));
                        s_h2[oc1 * 25 + qo] = fmaxf(p1 + bias21, 0.f);
                    }
                }
            }
        }
    }
    __syncthreads();

    // ---------------- Phase 4: fc1 (500->50, bf16 weights) split 5-way + relu, both images ----------------
    if (tid < 500) {
        const int im = (tid >= 250) ? 1 : 0;
        const int r = tid - 250 * im;
        const int oc = r / 5, part = r % 5;
        const unsigned* wr = (const unsigned*)(ws + 16384 + oc * 500 + part * 100);
        const float* hp = s_aux + im * AUXF + part * 100;
        float a = 0.f;
        #pragma unroll
        for (int i = 0; i < 25; ++i) {
            const float4 hv = *(const float4*)(hp + 4 * i);
            const unsigned ua = wr[2 * i], ub = wr[2 * i + 1];
            a += __uint_as_float(ua << 16)          * hv.x
               + __uint_as_float(ua & 0xffff0000u) * hv.y
               + __uint_as_float(ub << 16)          * hv.z
               + __uint_as_float(ub & 0xffff0000u) * hv.w;
        }
        s_aux[im * AUXF + 512 + r] = a;
    }
    __syncthreads();
    if (tid < 100) {
        const int im = (tid >= 50) ? 1 : 0;
        const int r = tid - 50 * im;
        float a = fb1[r];
        #pragma unroll
        for (int j = 0; j < 5; ++j) a += s_aux[im * AUXF + 512 + r * 5 + j];
        s_aux[im * AUXF + 768 + r] = fmaxf(a, 0.f);
    }
    __syncthreads();

    // ---------------- Phase 5: fc2 (50->10), both images ----------------
    if (tid < 20) {
        const int im = (tid >= 10) ? 1 : 0;
        const int r = tid - 10 * im;
        const float* wr = fw2 + r * 50;
        const float* f1 = s_aux + im * AUXF + 768;
        float a = fb2[r];
        for (int k = 0; k < 50; ++k) a += f1[k] * wr[k];
        s_aux[im * AUXF + 832 + r] = a;
    }
    __syncthreads();

    // ---------------- Phase 6: log_softmax, both images ----------------
    if (tid < 20) {
        const int im = (tid >= 10) ? 1 : 0;
        const int r = tid - 10 * im;
        const float* lg = s_aux + im * AUXF + 832;
        float m = lg[0];
        for (int k = 1; k < 10; ++k) m = fmaxf(m, lg[k]);
        float s = 0.f;
        for (int k = 0; k < 10; ++k) s += expf(lg[k] - m);
        out[(2 * (size_t)blockIdx.x + im) * 10 + r] = lg[r] - m - logf(s);
    }
}

extern "C" void kernel_launch(void* const* d_in, const int* in_sizes, int n_in,
                              void* d_out, int out_size, void* d_ws, size_t ws_size,
                              hipStream_t stream) {
    const float* x   = (const float*)d_in[0];
    const float* W   = (const float*)d_in[1];
    const float* w1  = (const float*)d_in[2];
    const float* b1  = (const float*)d_in[3];
    const float* w2  = (const float*)d_in[4];
    const float* b2  = (const float*)d_in[5];
    const float* fw1 = (const float*)d_in[6];
    const float* fb1 = (const float*)d_in[7];
    const float* fw2 = (const float*)d_in[8];
    const float* fb2 = (const float*)d_in[9];
    float* o = (float*)d_out;
    unsigned short* wsp = (unsigned short*)d_ws;

    const int B = in_sizes[0] / 3072;
    prepack<<<dim3(31), dim3(64), 0, stream>>>(W, w1, w2, wsp);
    pack_fc1<<<dim3(49), dim3(256), 0, stream>>>(fw1, wsp);
    fused_net<<<dim3(B / 2), dim3(512), 0, stream>>>(x, wsp, b1, b2, fb1, fw2, fb2, o);
}

// Round 12
// 109.954 us; speedup vs baseline: 2.2506x; 1.0840x over previous
//
#include <hip/hip_runtime.h>
#include <math.h>

// Fused net, round 12: RS1 136 -> 160 (single change + pad-zero loops).
// Phase-2 A-reads (the dominant ~1040 wave ds_read_b64/block) have bank-PAIR index
// (RS1/4*ci + cj + grp) mod 16. RS1/4 == 8 mod 16 makes each 16-lane group cover all
// 16 pairs exactly once (verified incl. oi-row crossings; grp rotates by +1) ->
// wave b64 reads hit the 4-cycle hardware floor, zero above-floor conflicts.
// Everything else identical to round 11 (2 img/block, 512 thr, streamed/staged B).

typedef __attribute__((ext_vector_type(8))) short bf16x8;
typedef __attribute__((ext_vector_type(4))) float f32x4;

union Frag { short4 h[2]; bf16x8 v; };

static __device__ __forceinline__ unsigned short f2bf(float f) {
    union { float f; unsigned u; } v; v.f = f;
    unsigned r = v.u + 0x7FFFu + ((v.u >> 16) & 1u);   // RNE
    return (unsigned short)(r >> 16);
}

#define MFMA(a, b, c) __builtin_amdgcn_mfma_f32_16x16x32_bf16((a), (b), (c), 0, 0, 0)

// ---------------- B-fragment prepack: 31 frags x 64 lanes x 8 bf16 ----------------
// fid 0..5  : linear  B[k][j]=W[j][k], fid=ks*3+nt (K=48 -> 2 steps, N=48 -> 3 tiles)
// fid 6..10 : conv1   ky=fid-6; window elem e=kx*4+icp (pixel stride 4)
// fid 11..30: conv2   fid-11 = nt*10+ky*2+s; window elem idx=32s+kap, idx=kx*12+icp
__global__ __launch_bounds__(64)
void prepack(const float* __restrict__ W, const float* __restrict__ w1,
             const float* __restrict__ w2, unsigned short* __restrict__ ws) {
    const int fid = blockIdx.x;
    const int lane = threadIdx.x;
    const int col = lane & 15, grp = lane >> 4;
    unsigned short tmp[8];
    #pragma unroll
    for (int e = 0; e < 8; ++e) {
        const int kap = 16 * (e >> 2) + 4 * grp + (e & 3);   // 0..31
        float v = 0.f;
        if (fid < 6) {
            const int ks = fid / 3, nt = fid % 3;
            const int k = 32 * ks + kap, j = 16 * nt + col;
            if (k < 48) v = W[j * 48 + k];
        } else if (fid < 11) {
            const int ky = fid - 6;
            const int kx = kap >> 2, icp = kap & 3;
            if (kx < 5 && icp < 3 && col < 10)
                v = w1[col * 75 + icp * 25 + ky * 5 + kx];
        } else {
            const int r = fid - 11, nt = r / 10, ky = (r % 10) >> 1, s = r & 1;
            const int idx = 32 * s + kap;
            const int kx = idx / 12, icp = idx % 12, oc = 16 * nt + col;
            if (kx < 5 && icp < 10 && oc < 20)
                v = w2[oc * 250 + icp * 25 + ky * 5 + kx];
        }
        tmp[e] = f2bf(v);
    }
    Frag f;
    f.h[0] = make_short4((short)tmp[0], (short)tmp[1], (short)tmp[2], (short)tmp[3]);
    f.h[1] = make_short4((short)tmp[4], (short)tmp[5], (short)tmp[6], (short)tmp[7]);
    *(bf16x8*)(ws + fid * 512 + lane * 8) = f.v;
}

// ---------------- fc1 weight pack: fw1 [50,500] f32 -> bf16 pairs at ws+16384 ----------------
__global__ __launch_bounds__(256)
void pack_fc1(const float* __restrict__ fw1, unsigned short* __restrict__ ws) {
    const int i = blockIdx.x * 256 + threadIdx.x;   // uint index, 12500 total
    if (i < 12500) {
        const unsigned lo = f2bf(fw1[2 * i]);
        const unsigned hi = f2bf(fw1[2 * i + 1]);
        ((unsigned*)(ws + 16384))[i] = lo | (hi << 16);
    }
}

// ---------------- main fused kernel: one block (512 thr) per TWO images ----------------
#define RS1 160              // s_img row stride: 32 px * 4ch = 128 used + 32 pad; RS1/4==8 mod 16
#define IMG_SZ 5184          // 32*RS1 + 64 tail (ushorts, 8-divisible)
#define RS2 168              // s_h1 row stride (elems): 14 cols * 12ch
#define H1_SZ 2416           // 14*RS2 + 64 tail
#define AUXF 848             // per-image aux floats: h2 512 | part 256 | f1 64 | lg 16

__global__ __launch_bounds__(512)
void fused_net(const float* __restrict__ x,    // [B,32,32,3] NHWC f32
               const unsigned short* __restrict__ ws, // prepacked B-frags + bf16 fc1 w
               const float* __restrict__ b1,   // [10]
               const float* __restrict__ b2,   // [20]
               const float* __restrict__ fb1,  // [50]
               const float* __restrict__ fw2,  // [10,50]
               const float* __restrict__ fb2,  // [10]
               float* __restrict__ out)        // [B,10]
{
    const int tid  = threadIdx.x;
    const int wave = __builtin_amdgcn_readfirstlane(tid >> 6);   // 0..7
    const int img  = wave >> 2;                                  // 0..1
    const int wv   = wave & 3;                                   // old 4-wave id
    const int lane = tid & 63;
    const int col16 = lane & 15, grp = lane >> 4;

    // s_pool: phases 1-2 = imgA[0,IMG_SZ) imgB[IMG_SZ,2*IMG_SZ); phase >=3 = s_b2[0,10240)
    __shared__ __align__(16) unsigned short s_pool[2 * IMG_SZ];
    __shared__ __align__(16) unsigned short s_h1[2 * H1_SZ];
    __shared__ __align__(16) float s_aux[2 * AUXF];

    unsigned short* s_img = s_pool + img * IMG_SZ;
    unsigned short* s_h1i = s_h1 + img * H1_SZ;
    unsigned short* s_b2  = s_pool;
    float* aux    = s_aux + img * AUXF;
    float* s_h2   = aux;            // 512 (500 used)

    const size_t bb = (size_t)(2 * blockIdx.x + img);   // batch index of this wave's image

    // ---------------- Phase 1: linear via MFMA -> s_img (HWC4 bf16) ----------------
    {
        const int blkA = 16 * wv + col16;
        const float* xb = x + bb * 3072 + (blkA >> 3) * 384 + (blkA & 7) * 12;
        const int k0 = 4 * grp,      o0 = (k0 / 12) * 96 + (k0 % 12);
        const int k1 = 16 + 4 * grp, o1 = (k1 / 12) * 96 + (k1 % 12);
        const int k2 = 32 + 4 * grp, o2 = (k2 / 12) * 96 + (k2 % 12);
        const float4 fa = *(const float4*)(xb + o0);
        const float4 fb = *(const float4*)(xb + o1);
        const float4 fc = *(const float4*)(xb + o2);
        Frag a0, a1;
        a0.h[0] = make_short4((short)f2bf(fa.x), (short)f2bf(fa.y), (short)f2bf(fa.z), (short)f2bf(fa.w));
        a0.h[1] = make_short4((short)f2bf(fb.x), (short)f2bf(fb.y), (short)f2bf(fb.z), (short)f2bf(fb.w));
        a1.h[0] = make_short4((short)f2bf(fc.x), (short)f2bf(fc.y), (short)f2bf(fc.z), (short)f2bf(fc.w));
        a1.h[1] = make_short4(0, 0, 0, 0);        // k>=48 pad: zero (also avoids OOB x reads)

        #pragma unroll
        for (int nt = 0; nt < 3; ++nt) {
            Frag bl0, bl1;                        // streamed from L2 (shared by both images)
            bl0.v = *(const bf16x8*)(ws + nt * 512 + lane * 8);
            bl1.v = *(const bf16x8*)(ws + (3 + nt) * 512 + lane * 8);
            f32x4 acc = {0.f, 0.f, 0.f, 0.f};
            acc = MFMA(a0.v, bl0.v, acc);
            acc = MFMA(a1.v, bl1.v, acc);
            const int j = 16 * nt + col16;                 // output k' index
            const int di = j / 12, dj = (j % 12) / 3, cch = j % 3;
            #pragma unroll
            for (int r = 0; r < 4; ++r) {
                const int blk = 16 * wv + 4 * grp + r;     // C row = block id
                const int row = (blk >> 3) * 4 + di, cp = (blk & 7) * 4 + dj;
                s_img[row * RS1 + cp * 4 + cch] = f2bf(acc[r]);
            }
        }
    }
    // zero pad-channel 3, row pads (cols 128..159), and LDS tails for BOTH images
    for (int p = tid; p < 2048; p += 512) {                 // ch-3 of 1024 px per image
        unsigned short* si = s_pool + (p >> 10) * IMG_SZ;
        const int q = p & 1023;
        si[(q >> 5) * RS1 + (q & 31) * 4 + 3] = 0;
    }
    for (int p = tid; p < 2048; p += 512) {                 // 32 pad cols x 32 rows per image
        unsigned short* si = s_pool + (p >> 10) * IMG_SZ;
        const int q = p & 1023;
        si[(q >> 5) * RS1 + 128 + (q & 31)] = 0;
    }
    if (tid < 128) s_pool[(tid >> 6) * IMG_SZ + 32 * RS1 + (tid & 63)] = 0;
    if (tid < 128) s_h1[(tid >> 6) * H1_SZ + 14 * RS2 + (tid & 63)] = 0;
    __syncthreads();

    // ---------------- Phase 2: conv1+pool+relu via MFMA -> s_h1 (HWC12 bf16) ----------------
    {
        Frag bc1[5];                              // resident across t-loop
        #pragma unroll
        for (int f = 0; f < 5; ++f)
            bc1[f].v = *(const bf16x8*)(ws + (6 + f) * 512 + lane * 8);
        const float bias1 = b1[col16 < 10 ? col16 : 0];

        for (int t = wv; t < 49; t += 4) {
            const int q = 4 * t + (col16 >> 2), sub = col16 & 3;   // A row m = col16
            const int oi = q / 14, oj = q % 14;
            const int ci = 2 * oi + (sub >> 1), cj = 2 * oj + (sub & 1);
            const int base = ci * RS1 + cj * 4 + 4 * grp;
            f32x4 acc = {0.f, 0.f, 0.f, 0.f};
            #pragma unroll
            for (int ky = 0; ky < 5; ++ky) {
                Frag a;
                a.h[0] = *(const short4*)&s_img[base + ky * RS1];
                a.h[1] = *(const short4*)&s_img[base + ky * RS1 + 16];
                acc = MFMA(a.v, bc1[ky].v, acc);
            }
            const int qo = 4 * t + grp;          // C rows 4*grp..+3 = one pool quad
            if (col16 < 12) {
                const float pm = fmaxf(fmaxf(acc[0], acc[1]), fmaxf(acc[2], acc[3]));
                const float val = fmaxf(pm + bias1, 0.f);
                s_h1i[(qo / 14) * RS2 + (qo % 14) * 12 + col16] =
                    (col16 < 10) ? f2bf(val) : (unsigned short)0;
            }
        }
    }
    __syncthreads();

    // ---- re-stage conv2 B-frags (20KB) into s_pool (both s_img now dead) ----
    {
        const uint4* src = (const uint4*)(ws + 11 * 512);   // frags 11..30, 1280 uint4
        uint4* dst = (uint4*)s_pool;
        dst[tid]       = src[tid];
        dst[tid + 512] = src[tid + 512];
        if (tid < 256) dst[tid + 1024] = src[tid + 1024];
    }
    __syncthreads();

    // ---------------- Phase 3: conv2+pool+relu via MFMA -> s_h2 (f32, flatten order) ----------------
    // (ky,s) outer, t inner: each B-frag pair read once per K-step. acc static-indexed.
    {
        const int oc1 = 16 + col16;
        const float bias20 = b2[col16];                    // col16 <= 15 < 20
        const float bias21 = b2[oc1 < 20 ? oc1 : 0];

        int baseA[2];
        #pragma unroll
        for (int tt = 0; tt < 2; ++tt) {
            const int t = wv + 4 * tt;                     // t in {wv, wv+4}
            int q = 4 * t + (col16 >> 2); if (q > 24) q = 24;   // clamp keeps reads in-bounds
            const int sub = col16 & 3;
            const int oi = q / 5, oj = q % 5;
            const int ci = 2 * oi + (sub >> 1), cj = 2 * oj + (sub & 1);
            baseA[tt] = ci * RS2 + cj * 12 + 4 * grp;
        }

        f32x4 accA0 = {0.f,0.f,0.f,0.f}, accA1 = {0.f,0.f,0.f,0.f};   // tile tt=0: N-tile 0/1
        f32x4 accB0 = {0.f,0.f,0.f,0.f}, accB1 = {0.f,0.f,0.f,0.f};   // tile tt=1
        #pragma unroll
        for (int ky = 0; ky < 5; ++ky) {
            #pragma unroll
            for (int s = 0; s < 2; ++s) {
                Frag bb0, bb1;
                bb0.v = *(const bf16x8*)(s_b2 + (ky * 2 + s) * 512 + lane * 8);
                bb1.v = *(const bf16x8*)(s_b2 + (10 + ky * 2 + s) * 512 + lane * 8);
                Frag a0, a1;
                a0.h[0] = *(const short4*)&s_h1i[baseA[0] + ky * RS2 + 32 * s];
                a0.h[1] = *(const short4*)&s_h1i[baseA[0] + ky * RS2 + 32 * s + 16];
                a1.h[0] = *(const short4*)&s_h1i[baseA[1] + ky * RS2 + 32 * s];
                a1.h[1] = *(const short4*)&s_h1i[baseA[1] + ky * RS2 + 32 * s + 16];
                accA0 = MFMA(a0.v, bb0.v, accA0);
                accA1 = MFMA(a0.v, bb1.v, accA1);
                accB0 = MFMA(a1.v, bb0.v, accB0);
                accB1 = MFMA(a1.v, bb1.v, accB1);
            }
        }
        #pragma unroll
        for (int tt = 0; tt < 2; ++tt) {
            const int t = wv + 4 * tt;
            if (t < 7) {
                const f32x4 c0 = tt ? accB0 : accA0;
                const f32x4 c1 = tt ? accB1 : accA1;
                const int qo = 4 * t + grp;
                if (qo < 25) {
                    const float p0 = fmaxf(fmaxf(c0[0], c0[1]), fmaxf(c0[2], c0[3]));
                    s_h2[col16 * 25 + qo] = fmaxf(p0 + bias20, 0.f);
                    if (oc1 < 20) {
                        const float p1 = fmaxf(fmaxf(c1[0], c1[1]), fmaxf(c1[2], c1[3]));
                        s_h2[oc1 * 25 + qo] = fmaxf(p1 + bias21, 0.f);
                    }
                }
            }
        }
    }
    __syncthreads();

    // ---------------- Phase 4: fc1 (500->50, bf16 weights) split 5-way + relu, both images ----------------
    if (tid < 500) {
        const int im = (tid >= 250) ? 1 : 0;
        const int r = tid - 250 * im;
        const int oc = r / 5, part = r % 5;
        const unsigned* wr = (const unsigned*)(ws + 16384 + oc * 500 + part * 100);
        const float* hp = s_aux + im * AUXF + part * 100;
        float a = 0.f;
        #pragma unroll
        for (int i = 0; i < 25; ++i) {
            const float4 hv = *(const float4*)(hp + 4 * i);
            const unsigned ua = wr[2 * i], ub = wr[2 * i + 1];
            a += __uint_as_float(ua << 16)          * hv.x
               + __uint_as_float(ua & 0xffff0000u) * hv.y
               + __uint_as_float(ub << 16)          * hv.z
               + __uint_as_float(ub & 0xffff0000u) * hv.w;
        }
        s_aux[im * AUXF + 512 + r] = a;
    }
    __syncthreads();
    if (tid < 100) {
        const int im = (tid >= 50) ? 1 : 0;
        const int r = tid - 50 * im;
        float a = fb1[r];
        #pragma unroll
        for (int j = 0; j < 5; ++j) a += s_aux[im * AUXF + 512 + r * 5 + j];
        s_aux[im * AUXF + 768 + r] = fmaxf(a, 0.f);
    }
    __syncthreads();

    // ---------------- Phase 5: fc2 (50->10), both images ----------------
    if (tid < 20) {
        const int im = (tid >= 10) ? 1 : 0;
        const int r = tid - 10 * im;
        const float* wr = fw2 + r * 50;
        const float* f1 = s_aux + im * AUXF + 768;
        float a = fb2[r];
        for (int k = 0; k < 50; ++k) a += f1[k] * wr[k];
        s_aux[im * AUXF + 832 + r] = a;
    }
    __syncthreads();

    // ---------------- Phase 6: log_softmax, both images ----------------
    if (tid < 20) {
        const int im = (tid >= 10) ? 1 : 0;
        const int r = tid - 10 * im;
        const float* lg = s_aux + im * AUXF + 832;
        float m = lg[0];
        for (int k = 1; k < 10; ++k) m = fmaxf(m, lg[k]);
        float s = 0.f;
        for (int k = 0; k < 10; ++k) s += expf(lg[k] - m);
        out[(2 * (size_t)blockIdx.x + im) * 10 + r] = lg[r] - m - logf(s);
    }
}

extern "C" void kernel_launch(void* const* d_in, const int* in_sizes, int n_in,
                              void* d_out, int out_size, void* d_ws, size_t ws_size,
                              hipStream_t stream) {
    const float* x   = (const float*)d_in[0];
    const float* W   = (const float*)d_in[1];
    const float* w1  = (const float*)d_in[2];
    const float* b1  = (const float*)d_in[3];
    const float* w2  = (const float*)d_in[4];
    const float* b2  = (const float*)d_in[5];
    const float* fw1 = (const float*)d_in[6];
    const float* fb1 = (const float*)d_in[7];
    const float* fw2 = (const float*)d_in[8];
    const float* fb2 = (const float*)d_in[9];
    float* o = (float*)d_out;
    unsigned short* wsp = (unsigned short*)d_ws;

    const int B = in_sizes[0] / 3072;
    prepack<<<dim3(31), dim3(64), 0, stream>>>(W, w1, w2, wsp);
    pack_fc1<<<dim3(49), dim3(256), 0, stream>>>(fw1, wsp);
    fused_net<<<dim3(B / 2), dim3(512), 0, stream>>>(x, wsp, b1, b2, fb1, fw2, fb2, o);
}

// Round 13
// 89.150 us; speedup vs baseline: 2.7758x; 1.2334x over previous
//
#include <hip/hip_runtime.h>
#include <math.h>

// Fused net, round 13: fc1 via MFMA.
// Round-12 budget: VALU 51% (top pipe); fc1's scalar bf16-unpack FMAs ~27% of all
// cycles. Replace phase 4 with MFMA: C[out][img] = sum_k fw1[out][k]*h2[img][k];
// A = prepacked fw1 frags (4 out-tiles x 16 k-steps, zero-padded), B = h2 stored
// bf16 in s_h2b[2][512] (phase-3 epilogue writes f2bf; pads zeroed). Wave w:
// out-tile=wv, k-half=img, 8 MFMA each; partials reduced via 256-float LDS.
// Everything else = round 12 (RS1=160 conflict-free, 2 img/block, 512 thr).

typedef __attribute__((ext_vector_type(8))) short bf16x8;
typedef __attribute__((ext_vector_type(4))) float f32x4;

union Frag { short4 h[2]; bf16x8 v; };

static __device__ __forceinline__ unsigned short f2bf(float f) {
    union { float f; unsigned u; } v; v.f = f;
    unsigned r = v.u + 0x7FFFu + ((v.u >> 16) & 1u);   // RNE
    return (unsigned short)(r >> 16);
}

#define MFMA(a, b, c) __builtin_amdgcn_mfma_f32_16x16x32_bf16((a), (b), (c), 0, 0, 0)

// ---------------- B-fragment prepack: 31 frags x 64 lanes x 8 bf16 ----------------
// fid 0..5  : linear  B[k][j]=W[j][k], fid=ks*3+nt (K=48 -> 2 steps, N=48 -> 3 tiles)
// fid 6..10 : conv1   ky=fid-6; window elem e=kx*4+icp (pixel stride 4)
// fid 11..30: conv2   fid-11 = nt*10+ky*2+s; window elem idx=32s+kap, idx=kx*12+icp
__global__ __launch_bounds__(64)
void prepack(const float* __restrict__ W, const float* __restrict__ w1,
             const float* __restrict__ w2, unsigned short* __restrict__ ws) {
    const int fid = blockIdx.x;
    const int lane = threadIdx.x;
    const int col = lane & 15, grp = lane >> 4;
    unsigned short tmp[8];
    #pragma unroll
    for (int e = 0; e < 8; ++e) {
        const int kap = 16 * (e >> 2) + 4 * grp + (e & 3);   // 0..31
        float v = 0.f;
        if (fid < 6) {
            const int ks = fid / 3, nt = fid % 3;
            const int k = 32 * ks + kap, j = 16 * nt + col;
            if (k < 48) v = W[j * 48 + k];
        } else if (fid < 11) {
            const int ky = fid - 6;
            const int kx = kap >> 2, icp = kap & 3;
            if (kx < 5 && icp < 3 && col < 10)
                v = w1[col * 75 + icp * 25 + ky * 5 + kx];
        } else {
            const int r = fid - 11, nt = r / 10, ky = (r % 10) >> 1, s = r & 1;
            const int idx = 32 * s + kap;
            const int kx = idx / 12, icp = idx % 12, oc = 16 * nt + col;
            if (kx < 5 && icp < 10 && oc < 20)
                v = w2[oc * 250 + icp * 25 + ky * 5 + kx];
        }
        tmp[e] = f2bf(v);
    }
    Frag f;
    f.h[0] = make_short4((short)tmp[0], (short)tmp[1], (short)tmp[2], (short)tmp[3]);
    f.h[1] = make_short4((short)tmp[4], (short)tmp[5], (short)tmp[6], (short)tmp[7]);
    *(bf16x8*)(ws + fid * 512 + lane * 8) = f.v;
}

// ---------------- fc1 A-frag prepack: 64 frags (kstep*4+mt) at ws+16384 ----------------
// A[m][k]: lane col = output row m (out = 16*mt+col), k = 32*kstep + kap. Zero-padded.
__global__ __launch_bounds__(64)
void pack_fc1(const float* __restrict__ fw1, unsigned short* __restrict__ ws) {
    const int fid = blockIdx.x;                 // 0..63 = kstep*4 + mt
    const int kstep = fid >> 2, mt = fid & 3;
    const int lane = threadIdx.x;
    const int col = lane & 15, grp = lane >> 4;
    const int outr = 16 * mt + col;
    unsigned short tmp[8];
    #pragma unroll
    for (int e = 0; e < 8; ++e) {
        const int kap = 16 * (e >> 2) + 4 * grp + (e & 3);
        const int kk = 32 * kstep + kap;
        float v = (outr < 50 && kk < 500) ? fw1[outr * 500 + kk] : 0.f;
        tmp[e] = f2bf(v);
    }
    Frag f;
    f.h[0] = make_short4((short)tmp[0], (short)tmp[1], (short)tmp[2], (short)tmp[3]);
    f.h[1] = make_short4((short)tmp[4], (short)tmp[5], (short)tmp[6], (short)tmp[7]);
    *(bf16x8*)(ws + 16384 + fid * 512 + lane * 8) = f.v;
}

// ---------------- main fused kernel: one block (512 thr) per TWO images ----------------
#define RS1 160              // s_img row stride: RS1/4==8 mod 16 -> conflict-free phase-2 reads
#define IMG_SZ 5184          // 32*RS1 + 64 tail (ushorts)
#define RS2 168              // s_h1 row stride (elems): 14 cols * 12ch
#define H1_SZ 2416           // 14*RS2 + 64 tail

__global__ __launch_bounds__(512)
void fused_net(const float* __restrict__ x,    // [B,32,32,3] NHWC f32
               const unsigned short* __restrict__ ws, // prepacked frags
               const float* __restrict__ b1,   // [10]
               const float* __restrict__ b2,   // [20]
               const float* __restrict__ fb1,  // [50]
               const float* __restrict__ fw2,  // [10,50]
               const float* __restrict__ fb2,  // [10]
               float* __restrict__ out)        // [B,10]
{
    const int tid  = threadIdx.x;
    const int wave = __builtin_amdgcn_readfirstlane(tid >> 6);   // 0..7
    const int img  = wave >> 2;                                  // 0..1
    const int wv   = wave & 3;                                   // old 4-wave id
    const int lane = tid & 63;
    const int col16 = lane & 15, grp = lane >> 4;

    // s_pool: phases 1-2 = imgA[0,IMG_SZ) imgB[IMG_SZ,2*IMG_SZ); phase >=3 = s_b2[0,10240)
    __shared__ __align__(16) unsigned short s_pool[2 * IMG_SZ];
    __shared__ __align__(16) unsigned short s_h1[2 * H1_SZ];
    __shared__ __align__(16) unsigned short s_h2b[2 * 512];   // h2 bf16, zero-padded 500..511
    __shared__ __align__(16) float s_aux[416];   // part 256 | f1 2x64 | lg 2x16

    unsigned short* s_img = s_pool + img * IMG_SZ;
    unsigned short* s_h1i = s_h1 + img * H1_SZ;
    unsigned short* s_b2  = s_pool;
    float* s_part = s_aux;          // [khalf*2+im][64]
    float* s_f1   = s_aux + 256;    // [im][64]
    float* s_lg   = s_aux + 384;    // [im][16]

    const size_t bb = (size_t)(2 * blockIdx.x + img);   // batch index of this wave's image

    // ---------------- Phase 1: linear via MFMA -> s_img (HWC4 bf16) ----------------
    {
        const int blkA = 16 * wv + col16;
        const float* xb = x + bb * 3072 + (blkA >> 3) * 384 + (blkA & 7) * 12;
        const int k0 = 4 * grp,      o0 = (k0 / 12) * 96 + (k0 % 12);
        const int k1 = 16 + 4 * grp, o1 = (k1 / 12) * 96 + (k1 % 12);
        const int k2 = 32 + 4 * grp, o2 = (k2 / 12) * 96 + (k2 % 12);
        const float4 fa = *(const float4*)(xb + o0);
        const float4 fb = *(const float4*)(xb + o1);
        const float4 fc = *(const float4*)(xb + o2);
        Frag a0, a1;
        a0.h[0] = make_short4((short)f2bf(fa.x), (short)f2bf(fa.y), (short)f2bf(fa.z), (short)f2bf(fa.w));
        a0.h[1] = make_short4((short)f2bf(fb.x), (short)f2bf(fb.y), (short)f2bf(fb.z), (short)f2bf(fb.w));
        a1.h[0] = make_short4((short)f2bf(fc.x), (short)f2bf(fc.y), (short)f2bf(fc.z), (short)f2bf(fc.w));
        a1.h[1] = make_short4(0, 0, 0, 0);        // k>=48 pad: zero (also avoids OOB x reads)

        #pragma unroll
        for (int nt = 0; nt < 3; ++nt) {
            Frag bl0, bl1;                        // streamed from L2 (shared by both images)
            bl0.v = *(const bf16x8*)(ws + nt * 512 + lane * 8);
            bl1.v = *(const bf16x8*)(ws + (3 + nt) * 512 + lane * 8);
            f32x4 acc = {0.f, 0.f, 0.f, 0.f};
            acc = MFMA(a0.v, bl0.v, acc);
            acc = MFMA(a1.v, bl1.v, acc);
            const int j = 16 * nt + col16;                 // output k' index
            const int di = j / 12, dj = (j % 12) / 3, cch = j % 3;
            #pragma unroll
            for (int r = 0; r < 4; ++r) {
                const int blk = 16 * wv + 4 * grp + r;     // C row = block id
                const int row = (blk >> 3) * 4 + di, cp = (blk & 7) * 4 + dj;
                s_img[row * RS1 + cp * 4 + cch] = f2bf(acc[r]);
            }
        }
    }
    // zero pad-channel 3, row pads (cols 128..159), LDS tails, h2b pads: no uninit reads ever
    for (int p = tid; p < 2048; p += 512) {                 // ch-3 of 1024 px per image
        unsigned short* si = s_pool + (p >> 10) * IMG_SZ;
        const int q = p & 1023;
        si[(q >> 5) * RS1 + (q & 31) * 4 + 3] = 0;
    }
    for (int p = tid; p < 2048; p += 512) {                 // 32 pad cols x 32 rows per image
        unsigned short* si = s_pool + (p >> 10) * IMG_SZ;
        const int q = p & 1023;
        si[(q >> 5) * RS1 + 128 + (q & 31)] = 0;
    }
    if (tid < 128) s_pool[(tid >> 6) * IMG_SZ + 32 * RS1 + (tid & 63)] = 0;
    if (tid < 128) s_h1[(tid >> 6) * H1_SZ + 14 * RS2 + (tid & 63)] = 0;
    if (tid < 24) s_h2b[(tid / 12) * 512 + 500 + (tid % 12)] = 0;
    __syncthreads();

    // ---------------- Phase 2: conv1+pool+relu via MFMA -> s_h1 (HWC12 bf16) ----------------
    {
        Frag bc1[5];                              // resident across t-loop
        #pragma unroll
        for (int f = 0; f < 5; ++f)
            bc1[f].v = *(const bf16x8*)(ws + (6 + f) * 512 + lane * 8);
        const float bias1 = b1[col16 < 10 ? col16 : 0];

        for (int t = wv; t < 49; t += 4) {
            const int q = 4 * t + (col16 >> 2), sub = col16 & 3;   // A row m = col16
            const int oi = q / 14, oj = q % 14;
            const int ci = 2 * oi + (sub >> 1), cj = 2 * oj + (sub & 1);
            const int base = ci * RS1 + cj * 4 + 4 * grp;
            f32x4 acc = {0.f, 0.f, 0.f, 0.f};
            #pragma unroll
            for (int ky = 0; ky < 5; ++ky) {
                Frag a;
                a.h[0] = *(const short4*)&s_img[base + ky * RS1];
                a.h[1] = *(const short4*)&s_img[base + ky * RS1 + 16];
                acc = MFMA(a.v, bc1[ky].v, acc);
            }
            const int qo = 4 * t + grp;          // C rows 4*grp..+3 = one pool quad
            if (col16 < 12) {
                const float pm = fmaxf(fmaxf(acc[0], acc[1]), fmaxf(acc[2], acc[3]));
                const float val = fmaxf(pm + bias1, 0.f);
                s_h1i[(qo / 14) * RS2 + (qo % 14) * 12 + col16] =
                    (col16 < 10) ? f2bf(val) : (unsigned short)0;
            }
        }
    }
    __syncthreads();

    // ---- re-stage conv2 B-frags (20KB) into s_pool (both s_img now dead) ----
    {
        const uint4* src = (const uint4*)(ws + 11 * 512);   // frags 11..30, 1280 uint4
        uint4* dst = (uint4*)s_pool;
        dst[tid]       = src[tid];
        dst[tid + 512] = src[tid + 512];
        if (tid < 256) dst[tid + 1024] = src[tid + 1024];
    }
    __syncthreads();

    // ---------------- Phase 3: conv2+pool+relu via MFMA -> s_h2b (bf16, flatten order) ----------------
    {
        const int oc1 = 16 + col16;
        const float bias20 = b2[col16];                    // col16 <= 15 < 20
        const float bias21 = b2[oc1 < 20 ? oc1 : 0];

        int baseA[2];
        #pragma unroll
        for (int tt = 0; tt < 2; ++tt) {
            const int t = wv + 4 * tt;                     // t in {wv, wv+4}
            int q = 4 * t + (col16 >> 2); if (q > 24) q = 24;   // clamp keeps reads in-bounds
            const int sub = col16 & 3;
            const int oi = q / 5, oj = q % 5;
            const int ci = 2 * oi + (sub >> 1), cj = 2 * oj + (sub & 1);
            baseA[tt] = ci * RS2 + cj * 12 + 4 * grp;
        }

        f32x4 accA0 = {0.f,0.f,0.f,0.f}, accA1 = {0.f,0.f,0.f,0.f};   // tile tt=0: N-tile 0/1
        f32x4 accB0 = {0.f,0.f,0.f,0.f}, accB1 = {0.f,0.f,0.f,0.f};   // tile tt=1
        #pragma unroll
        for (int ky = 0; ky < 5; ++ky) {
            #pragma unroll
            for (int s = 0; s < 2; ++s) {
                Frag bb0, bb1;
                bb0.v = *(const bf16x8*)(s_b2 + (ky * 2 + s) * 512 + lane * 8);
                bb1.v = *(const bf16x8*)(s_b2 + (10 + ky * 2 + s) * 512 + lane * 8);
                Frag a0, a1;
                a0.h[0] = *(const short4*)&s_h1i[baseA[0] + ky * RS2 + 32 * s];
                a0.h[1] = *(const short4*)&s_h1i[baseA[0] + ky * RS2 + 32 * s + 16];
                a1.h[0] = *(const short4*)&s_h1i[baseA[1] + ky * RS2 + 32 * s];
                a1.h[1] = *(const short4*)&s_h1i[baseA[1] + ky * RS2 + 32 * s + 16];
                accA0 = MFMA(a0.v, bb0.v, accA0);
                accA1 = MFMA(a0.v, bb1.v, accA1);
                accB0 = MFMA(a1.v, bb0.v, accB0);
                accB1 = MFMA(a1.v, bb1.v, accB1);
            }
        }
        unsigned short* h2 = s_h2b + img * 512;
        #pragma unroll
        for (int tt = 0; tt < 2; ++tt) {
            const int t = wv + 4 * tt;
            if (t < 7) {
                const f32x4 c0 = tt ? accB0 : accA0;
                const f32x4 c1 = tt ? accB1 : accA1;
                const int qo = 4 * t + grp;
                if (qo < 25) {
                    const float p0 = fmaxf(fmaxf(c0[0], c0[1]), fmaxf(c0[2], c0[3]));
                    h2[col16 * 25 + qo] = f2bf(fmaxf(p0 + bias20, 0.f));
                    if (oc1 < 20) {
                        const float p1 = fmaxf(fmaxf(c1[0], c1[1]), fmaxf(c1[2], c1[3]));
                        h2[oc1 * 25 + qo] = f2bf(fmaxf(p1 + bias21, 0.f));
                    }
                }
            }
        }
    }
    __syncthreads();

    // ---------------- Phase 4: fc1 via MFMA: C[out][img], wave = (khalf=img, mt=wv) ----------------
    {
        const int mt = wv, khalf = img;
        const int imc = col16 < 2 ? col16 : 0;     // B col = image; cols 2..15 unused
        f32x4 acc = {0.f, 0.f, 0.f, 0.f};
        #pragma unroll
        for (int j = 0; j < 8; ++j) {
            const int kstep = 8 * khalf + j;
            Frag af, bfv;
            af.v = *(const bf16x8*)(ws + 16384 + (kstep * 4 + mt) * 512 + lane * 8);
            bfv.h[0] = *(const short4*)&s_h2b[imc * 512 + 32 * kstep + 4 * grp];
            bfv.h[1] = *(const short4*)&s_h2b[imc * 512 + 32 * kstep + 16 + 4 * grp];
            acc = MFMA(af.v, bfv.v, acc);
        }
        if (col16 < 2) {
            #pragma unroll
            for (int r = 0; r < 4; ++r)
                s_part[(khalf * 2 + col16) * 64 + 16 * mt + 4 * grp + r] = acc[r];
        }
    }
    __syncthreads();
    if (tid < 128) {                                // combine k-halves, +bias, relu
        const int im = tid >> 6, o = tid & 63;
        const float a = s_part[im * 64 + o] + s_part[(2 + im) * 64 + o];
        if (o < 50) s_f1[im * 64 + o] = fmaxf(a + fb1[o], 0.f);
    }
    __syncthreads();

    // ---------------- Phase 5: fc2 (50->10), both images ----------------
    if (tid < 20) {
        const int im = (tid >= 10) ? 1 : 0;
        const int r = tid - 10 * im;
        const float* wr = fw2 + r * 50;
        const float* f1 = s_f1 + im * 64;
        float a = fb2[r];
        for (int k = 0; k < 50; ++k) a += f1[k] * wr[k];
        s_lg[im * 16 + r] = a;
    }
    __syncthreads();

    // ---------------- Phase 6: log_softmax, both images ----------------
    if (tid < 20) {
        const int im = (tid >= 10) ? 1 : 0;
        const int r = tid - 10 * im;
        const float* lg = s_lg + im * 16;
        float m = lg[0];
        for (int k = 1; k < 10; ++k) m = fmaxf(m, lg[k]);
        float s = 0.f;
        for (int k = 0; k < 10; ++k) s += expf(lg[k] - m);
        out[(2 * (size_t)blockIdx.x + im) * 10 + r] = lg[r] - m - logf(s);
    }
}

extern "C" void kernel_launch(void* const* d_in, const int* in_sizes, int n_in,
                              void* d_out, int out_size, void* d_ws, size_t ws_size,
                              hipStream_t stream) {
    const float* x   = (const float*)d_in[0];
    const float* W   = (const float*)d_in[1];
    const float* w1  = (const float*)d_in[2];
    const float* b1  = (const float*)d_in[3];
    const float* w2  = (const float*)d_in[4];
    const float* b2  = (const float*)d_in[5];
    const float* fw1 = (const float*)d_in[6];
    const float* fb1 = (const float*)d_in[7];
    const float* fw2 = (const float*)d_in[8];
    const float* fb2 = (const float*)d_in[9];
    float* o = (float*)d_out;
    unsigned short* wsp = (unsigned short*)d_ws;

    const int B = in_sizes[0] / 3072;
    prepack<<<dim3(31), dim3(64), 0, stream>>>(W, w1, w2, wsp);
    pack_fc1<<<dim3(64), dim3(64), 0, stream>>>(fw1, wsp);
    fused_net<<<dim3(B / 2), dim3(512), 0, stream>>>(x, wsp, b1, b2, fb1, fw2, fb2, o);
}